// Round 15
// baseline (375.988 us; speedup 1.0000x reference)
//
#include <hip/hip_runtime.h>
#include <hip/hip_bf16.h>

// Shapes (fixed by the problem)
#define B_  2
#define S_  2048
#define D_  1024
#define H_  16
#define HD_ 64
#define FF_ 4096
#define NT  (B_ * S_)          // 4096 tokens
#define SCALE_ 0.125f          // 1/sqrt(64)
#define KLOG2E 0.1803368801111f // SCALE * log2(e)
#define EPS_  1e-5f

typedef __attribute__((ext_vector_type(8))) short bf16x8;   // 8 bf16 = 4 VGPRs
typedef __attribute__((ext_vector_type(4))) float f32x4;    // MFMA C/D frag

__device__ inline short f2bf(float f) {
    __hip_bfloat16 h = __float2bfloat16(f);
    return __builtin_bit_cast(short, h);
}
__device__ inline float bf2f(unsigned short u) {
    __hip_bfloat16 h = __builtin_bit_cast(__hip_bfloat16, u);
    return __bfloat162float(h);
}
// packed f32x2 -> bf16x2 (v_cvt_pk_bf16_f32 on gfx950), lo in low 16 bits.
// NOTE: __hip_bfloat162 is NOT trivially copyable -> bit-cast members.
__device__ inline unsigned int pk2bf(float lo, float hi) {
    __hip_bfloat162 h = __float22bfloat162_rn(float2{lo, hi});
    const unsigned short l16 = __builtin_bit_cast(unsigned short, h.x);
    const unsigned short h16 = __builtin_bit_cast(unsigned short, h.y);
    return (unsigned int)l16 | ((unsigned int)h16 << 16);
}

#define GLOBAL_AS __attribute__((address_space(1)))
#define LDS_AS    __attribute__((address_space(3)))

// ---------------------------------------------------------------------------
// Dtype detection (verified working)
// ---------------------------------------------------------------------------
struct DetectArgs { const unsigned short* p[12]; int n[12]; };

__global__ __launch_bounds__(256) void detect_kernel(DetectArgs a, int* flags) {
    const int t = blockIdx.x;
    const unsigned short* s = a.p[t];
    const int cnt = min(a.n[t], 16384);
    const int tid = threadIdx.x;
    int huge = 0, zeven = 0;
    for (int i = tid; i < cnt; i += 256) {
        const unsigned short v = s[i];
        const int e = (v >> 7) & 0xFF;
        if (e >= 142) huge++;
        if (((i & 1) == 0) && ((v & 0x7FFF) == 0)) zeven++;
    }
    __shared__ int sh, sz;
    if (tid == 0) { sh = 0; sz = 0; }
    __syncthreads();
    atomicAdd(&sh, huge);
    atomicAdd(&sz, zeven);
    __syncthreads();
    if (tid == 0) flags[t] = (sh > 0 || sz * 4 > cnt) ? 1 : 0;
}

// x convert -> bf16; block 0..6 also convert the 7 small f32 vectors
struct VecArgs { const void* src[7]; float* dst[7]; int n[7]; int fidx[7]; };

__global__ __launch_bounds__(256) void conv_x_vecs_kernel(
    const void* __restrict__ src, unsigned short* __restrict__ dst, int n,
    VecArgs a, const int* __restrict__ flags)
{
    const int i = blockIdx.x * 256 + threadIdx.x;
    if (i < n) {
        if (flags[0])
            dst[i] = (unsigned short)f2bf(((const float*)src)[i]);
        else
            dst[i] = ((const unsigned short*)src)[i];
    }
    if (blockIdx.x < 7) {
        const int v = blockIdx.x;
        const int f = flags[a.fidx[v]];
        for (int j = threadIdx.x; j < a.n[v]; j += 256) {
            a.dst[v][j] = f ? ((const float*)a.src[v])[j]
                            : bf2f(((const unsigned short*)a.src[v])[j]);
        }
    }
}

// fused tiled transpose convert for all 4 weights: src [K,N] -> dst [N,K] bf16
struct TArgs {
    const void* src[4]; unsigned short* dst[4];
    int K[4], N[4], fidx[4], start[5];
};

__global__ __launch_bounds__(256) void conv_t_all_kernel(
    TArgs t, const int* __restrict__ flags)
{
    __shared__ short T[32][33];
    const int tile = blockIdx.x;
    int w = 0;
    if (tile >= t.start[1]) w = 1;
    if (tile >= t.start[2]) w = 2;
    if (tile >= t.start[3]) w = 3;
    const int rel = tile - t.start[w];
    const int K = t.K[w], N = t.N[w];
    const int tilesN = N / 32;
    const int kt = (rel / tilesN) * 32, nt = (rel % tilesN) * 32;
    const void* src = t.src[w];
    unsigned short* dst = t.dst[w];
    const int f = flags[t.fidx[w]];

    const int c  = threadIdx.x & 31;
    const int r0 = (threadIdx.x >> 5) * 4;
#pragma unroll
    for (int i = 0; i < 4; i++) {
        const int r = r0 + i;
        const size_t gi = (size_t)(kt + r) * N + nt + c;
        short v = f ? f2bf(((const float*)src)[gi])
                    : (short)((const unsigned short*)src)[gi];
        T[c][r] = v;
    }
    __syncthreads();
#pragma unroll
    for (int i = 0; i < 4; i++) {
        const int n = r0 + i;
        dst[(size_t)(nt + n) * K + kt + c] = (unsigned short)T[n][c];
    }
}

// ---------------------------------------------------------------------------
// 256x256 MFMA GEMM, 8 waves (512 thr), BK=32, 4-slot LDS ring with COUNTED
// vmcnt pipeline (T3+T4) — r9 verified. Used for ffn1 (grid 256 = 1/CU full
// coverage; r14 A/B showed the 128^2 ring was ~7us WORSE for ffn1: its 256^2
// grid had no coverage deficit, so 128^2 only doubled B-panel staging).
// ---------------------------------------------------------------------------
#define G256_STAGE(tile_)                                                     \
    do {                                                                      \
        char* sb_ = smem + (size_t)((tile_) & 3) * 32768;                     \
        const int kb_ = (tile_) << 5;                                         \
        __builtin_amdgcn_global_load_lds(                                     \
            (const GLOBAL_AS void*)(ag0 + kb_),                               \
            (LDS_AS void*)(sb_ + sdst2), 16, 0, 0);                           \
        __builtin_amdgcn_global_load_lds(                                     \
            (const GLOBAL_AS void*)(ag1 + kb_),                               \
            (LDS_AS void*)(sb_ + 8192 + sdst2), 16, 0, 0);                    \
        __builtin_amdgcn_global_load_lds(                                     \
            (const GLOBAL_AS void*)(bg0 + kb_),                               \
            (LDS_AS void*)(sb_ + 16384 + sdst2), 16, 0, 0);                   \
        __builtin_amdgcn_global_load_lds(                                     \
            (const GLOBAL_AS void*)(bg1 + kb_),                               \
            (LDS_AS void*)(sb_ + 24576 + sdst2), 16, 0, 0);                   \
    } while (0)

template<bool HAS_BIAS, bool RELU, bool QSCALE>
__global__ __launch_bounds__(512) void gemm256_kernel(
    const unsigned short* __restrict__ A,
    const unsigned short* __restrict__ Bt,
    const float* __restrict__ bias,
    unsigned short* __restrict__ out,
    int M, int N, int K)
{
    extern __shared__ char smem[];

    const int tid  = threadIdx.x;
    const int wave = tid >> 6;
    const int lane = tid & 63;
    const int quad = lane >> 4;
    const int l16  = lane & 15;
    const int wr   = wave >> 2;      // 0..1 -> 128-row half
    const int wc   = wave & 3;       // 0..3 -> 64-col slice

    const int row0 = blockIdx.x * 256;
    const int col0 = blockIdx.y * 256;

    // staging map: thread -> (row srow, swizzled k-slot); LDS dest is
    // wave-uniform base + lane*16B (gload_lds requirement, verified).
    const int srow  = tid >> 2;                                   // 0..127
    const int sk    = (((tid & 3) ^ ((srow >> 1) & 3)) * 8);      // swizzled
    const int sdst2 = srow * 64 + (tid & 3) * 16;                 // bytes
    const unsigned short* ag0 = A  + (size_t)(row0 + srow) * K + sk;
    const unsigned short* ag1 = A  + (size_t)(row0 + 128 + srow) * K + sk;
    const unsigned short* bg0 = Bt + (size_t)(col0 + srow) * K + sk;
    const unsigned short* bg1 = Bt + (size_t)(col0 + 128 + srow) * K + sk;

    // read-side swizzled slot (same derivation as 128^2 kernel)
    const int rsw = (quad ^ ((l16 >> 1) & 3)) * 8;

    const int NTk = K >> 5;          // K-tiles of 32

    f32x4 acc[8][4] = {};

    // prologue: stage tiles 0,1,2
    G256_STAGE(0);
    G256_STAGE(1);
    G256_STAGE(2);

    for (int t = 0; t < NTk; t++) {
        if (t + 2 < NTk)
            asm volatile("s_waitcnt vmcnt(8)\n\ts_barrier" ::: "memory");
        else if (t + 1 < NTk)
            asm volatile("s_waitcnt vmcnt(4)\n\ts_barrier" ::: "memory");
        else
            asm volatile("s_waitcnt vmcnt(0)\n\ts_barrier" ::: "memory");

        const short* sA = (const short*)(smem + (size_t)(t & 3) * 32768);
        const short* sB = sA + 8192;

        bf16x8 af[8], bfr[4];
#pragma unroll
        for (int mi = 0; mi < 8; mi++)
            af[mi] = *reinterpret_cast<const bf16x8*>(
                &sA[(wr * 128 + mi * 16 + l16) * 32 + rsw]);
#pragma unroll
        for (int ni = 0; ni < 4; ni++)
            bfr[ni] = *reinterpret_cast<const bf16x8*>(
                &sB[(wc * 64 + ni * 16 + l16) * 32 + rsw]);
#pragma unroll
        for (int mi = 0; mi < 8; mi++)
#pragma unroll
            for (int ni = 0; ni < 4; ni++)
                acc[mi][ni] = __builtin_amdgcn_mfma_f32_16x16x32_bf16(
                    af[mi], bfr[ni], acc[mi][ni], 0, 0, 0);

        if (t + 3 < NTk) G256_STAGE(t + 3);
    }

#pragma unroll
    for (int ni = 0; ni < 4; ni++) {
        const int col = col0 + wc * 64 + ni * 16 + l16;
        float badd = 0.f;
        if constexpr (HAS_BIAS) badd = bias[col];
        float qs = 1.f;
        if constexpr (QSCALE)
            qs = (((col0 + wc * 64 + ni * 16) % 192) < 64) ? KLOG2E : 1.f;
#pragma unroll
        for (int mi = 0; mi < 8; mi++) {
#pragma unroll
            for (int r = 0; r < 4; r++) {
                const int row = row0 + wr * 128 + mi * 16 + quad * 4 + r;
                float v = acc[mi][ni][r] + badd;
                if constexpr (QSCALE) v *= qs;
                if constexpr (RELU) v = fmaxf(v, 0.f);
                out[(size_t)row * N + col] = (unsigned short)f2bf(v);
            }
        }
    }
}

// ---------------------------------------------------------------------------
// NON-SPLIT 128x128 ring GEMM (4 waves, BK=32, 4-slot x 16 KB = 64 KB LDS,
// counted vmcnt) with bias/QSCALE/RELU bf16 epilogue. Used for qkv only:
// grid 32x24 = 768 blocks = 100% CU coverage at 2/CU (the 256^2 ring gave
// only 192 blocks = 75% of CUs for qkv's shape). r13 verified: session best.
// ---------------------------------------------------------------------------
#define G128R_STAGE(tile_)                                                    \
    do {                                                                      \
        char* sb_ = smem + (size_t)((tile_) & 3) * 16384;                     \
        const int kb_ = (tile_) << 5;                                         \
        __builtin_amdgcn_global_load_lds(                                     \
            (const GLOBAL_AS void*)(agp0 + kb_),                              \
            (LDS_AS void*)(sb_ + adst0), 16, 0, 0);                           \
        __builtin_amdgcn_global_load_lds(                                     \
            (const GLOBAL_AS void*)(agp1 + kb_),                              \
            (LDS_AS void*)(sb_ + adst1), 16, 0, 0);                           \
        __builtin_amdgcn_global_load_lds(                                     \
            (const GLOBAL_AS void*)(bgp0 + kb_),                              \
            (LDS_AS void*)(sb_ + 8192 + adst0), 16, 0, 0);                    \
        __builtin_amdgcn_global_load_lds(                                     \
            (const GLOBAL_AS void*)(bgp1 + kb_),                              \
            (LDS_AS void*)(sb_ + 8192 + adst1), 16, 0, 0);                    \
    } while (0)

template<bool HAS_BIAS, bool RELU, bool QSCALE>
__global__ __launch_bounds__(256) void gemm128r_kernel(
    const unsigned short* __restrict__ A,
    const unsigned short* __restrict__ Bt,
    const float* __restrict__ bias,
    unsigned short* __restrict__ out,
    int M, int N, int K)
{
    extern __shared__ char smem[];

    const int tid  = threadIdx.x;
    const int wave = tid >> 6;
    const int lane = tid & 63;
    const int quad = lane >> 4;
    const int l16  = lane & 15;

    const int row0 = blockIdx.x * 128;
    const int col0 = blockIdx.y * 128;

    const int ldrow = lane >> 2;                                 // 0..15
    const int ldk   = (((lane & 3) ^ ((ldrow >> 1) & 3)) * 8);   // swizzled
    const unsigned short* agp0 = A  + (size_t)(row0 + wave * 32 + ldrow) * K + ldk;
    const unsigned short* agp1 = agp0 + (size_t)16 * K;
    const unsigned short* bgp0 = Bt + (size_t)(col0 + wave * 32 + ldrow) * K + ldk;
    const unsigned short* bgp1 = bgp0 + (size_t)16 * K;

    const int adst0 = (wave * 32 + ldrow) * 64 + (lane & 3) * 16;
    const int adst1 = adst0 + 16 * 64;

    const int wm = (wave >> 1) * 64;
    const int wn = (wave & 1) * 64;
    const int rsw = (quad ^ ((l16 >> 1) & 3)) * 8;

    const int NTk = K >> 5;          // K-tiles of 32

    f32x4 acc[4][4] = {};

    // prologue: stage tiles 0,1,2
    G128R_STAGE(0);
    if (1 < NTk) G128R_STAGE(1);
    if (2 < NTk) G128R_STAGE(2);

    for (int t = 0; t < NTk; t++) {
        if (t + 2 < NTk)
            asm volatile("s_waitcnt vmcnt(8)\n\ts_barrier" ::: "memory");
        else if (t + 1 < NTk)
            asm volatile("s_waitcnt vmcnt(4)\n\ts_barrier" ::: "memory");
        else
            asm volatile("s_waitcnt vmcnt(0)\n\ts_barrier" ::: "memory");

        const short* sA = (const short*)(smem + (size_t)(t & 3) * 16384);
        const short* sB = sA + 4096;

        bf16x8 af[4], bfr[4];
#pragma unroll
        for (int mi = 0; mi < 4; mi++)
            af[mi] = *reinterpret_cast<const bf16x8*>(
                &sA[(wm + mi * 16 + l16) * 32 + rsw]);
#pragma unroll
        for (int ni = 0; ni < 4; ni++)
            bfr[ni] = *reinterpret_cast<const bf16x8*>(
                &sB[(wn + ni * 16 + l16) * 32 + rsw]);
#pragma unroll
        for (int mi = 0; mi < 4; mi++)
#pragma unroll
            for (int ni = 0; ni < 4; ni++)
                acc[mi][ni] = __builtin_amdgcn_mfma_f32_16x16x32_bf16(
                    af[mi], bfr[ni], acc[mi][ni], 0, 0, 0);

        if (t + 3 < NTk) G128R_STAGE(t + 3);
    }

#pragma unroll
    for (int ni = 0; ni < 4; ni++) {
        const int col = col0 + wn + ni * 16 + l16;
        float badd = 0.f;
        if constexpr (HAS_BIAS) badd = bias[col];
        float qs = 1.f;
        if constexpr (QSCALE)
            qs = (((col0 + wn + ni * 16) % 192) < 64) ? KLOG2E : 1.f;
#pragma unroll
        for (int mi = 0; mi < 4; mi++) {
#pragma unroll
            for (int r = 0; r < 4; r++) {
                const int row = row0 + wm + mi * 16 + quad * 4 + r;
                float v = acc[mi][ni][r] + badd;
                if constexpr (QSCALE) v *= qs;
                if constexpr (RELU) v = fmaxf(v, 0.f);
                out[(size_t)row * N + col] = (unsigned short)f2bf(v);
            }
        }
    }
}

// ---------------------------------------------------------------------------
// Split-K 128x128 GEMM, BK=32, 4-slot LDS ring with COUNTED vmcnt pipeline —
// r10 verified. Raw f32 partials. Used for wo and ffn2.
// ---------------------------------------------------------------------------
#define GSK_STAGE(tile_)                                                      \
    do {                                                                      \
        char* sb_ = smem + (size_t)((tile_) & 3) * 16384;                     \
        const int kb_ = (tile_) << 5;                                         \
        __builtin_amdgcn_global_load_lds(                                     \
            (const GLOBAL_AS void*)(agp0 + kb_),                              \
            (LDS_AS void*)(sb_ + adst0), 16, 0, 0);                           \
        __builtin_amdgcn_global_load_lds(                                     \
            (const GLOBAL_AS void*)(agp1 + kb_),                              \
            (LDS_AS void*)(sb_ + adst1), 16, 0, 0);                           \
        __builtin_amdgcn_global_load_lds(                                     \
            (const GLOBAL_AS void*)(bgp0 + kb_),                              \
            (LDS_AS void*)(sb_ + 8192 + adst0), 16, 0, 0);                    \
        __builtin_amdgcn_global_load_lds(                                     \
            (const GLOBAL_AS void*)(bgp1 + kb_),                              \
            (LDS_AS void*)(sb_ + 8192 + adst1), 16, 0, 0);                    \
    } while (0)

__global__ __launch_bounds__(256) void gemm128_sk_kernel(
    const unsigned short* __restrict__ A,
    const unsigned short* __restrict__ Bt,
    float* __restrict__ out0,
    float* __restrict__ out1,
    int M, int N, int K)
{
    extern __shared__ char smem[];

    const int tid  = threadIdx.x;
    const int wave = tid >> 6;
    const int lane = tid & 63;
    const int quad = lane >> 4;
    const int l16  = lane & 15;

    const int row0 = blockIdx.x * 128;
    const int col0 = blockIdx.y * 128;
    const int z    = blockIdx.z;
    const int Kh   = K >> 1;

    const unsigned short* Az  = A  + (size_t)z * Kh;
    const unsigned short* Btz = Bt + (size_t)z * Kh;
    float* out = z ? out1 : out0;

    const int ldrow = lane >> 2;                                 // 0..15
    const int ldk   = (((lane & 3) ^ ((ldrow >> 1) & 3)) * 8);   // swizzled
    const unsigned short* agp0 = Az  + (size_t)(row0 + wave * 32 + ldrow) * K + ldk;
    const unsigned short* agp1 = agp0 + (size_t)16 * K;
    const unsigned short* bgp0 = Btz + (size_t)(col0 + wave * 32 + ldrow) * K + ldk;
    const unsigned short* bgp1 = bgp0 + (size_t)16 * K;

    // LDS byte destinations within a slot (A at 0, B at +8192):
    // row = wave*32+ldrow (+16), 64 B/row, slot (lane&3)*16.
    const int adst0 = (wave * 32 + ldrow) * 64 + (lane & 3) * 16;
    const int adst1 = adst0 + 16 * 64;

    const int wm = (wave >> 1) * 64;
    const int wn = (wave & 1) * 64;
    const int rsw = (quad ^ ((l16 >> 1) & 3)) * 8;

    const int NTk = Kh >> 5;         // K-tiles of 32

    f32x4 acc[4][4] = {};

    // prologue: stage tiles 0,1,2
    GSK_STAGE(0);
    if (1 < NTk) GSK_STAGE(1);
    if (2 < NTk) GSK_STAGE(2);

    for (int t = 0; t < NTk; t++) {
        if (t + 2 < NTk)
            asm volatile("s_waitcnt vmcnt(8)\n\ts_barrier" ::: "memory");
        else if (t + 1 < NTk)
            asm volatile("s_waitcnt vmcnt(4)\n\ts_barrier" ::: "memory");
        else
            asm volatile("s_waitcnt vmcnt(0)\n\ts_barrier" ::: "memory");

        const short* sA = (const short*)(smem + (size_t)(t & 3) * 16384);
        const short* sB = sA + 4096;

        bf16x8 af[4], bfr[4];
#pragma unroll
        for (int mi = 0; mi < 4; mi++)
            af[mi] = *reinterpret_cast<const bf16x8*>(
                &sA[(wm + mi * 16 + l16) * 32 + rsw]);
#pragma unroll
        for (int ni = 0; ni < 4; ni++)
            bfr[ni] = *reinterpret_cast<const bf16x8*>(
                &sB[(wn + ni * 16 + l16) * 32 + rsw]);
#pragma unroll
        for (int mi = 0; mi < 4; mi++)
#pragma unroll
            for (int ni = 0; ni < 4; ni++)
                acc[mi][ni] = __builtin_amdgcn_mfma_f32_16x16x32_bf16(
                    af[mi], bfr[ni], acc[mi][ni], 0, 0, 0);

        if (t + 3 < NTk) GSK_STAGE(t + 3);
    }

#pragma unroll
    for (int ni = 0; ni < 4; ni++) {
        const int col = col0 + wn + ni * 16 + l16;
#pragma unroll
        for (int mi = 0; mi < 4; mi++)
#pragma unroll
            for (int r = 0; r < 4; r++) {
                const int row = row0 + wm + mi * 16 + quad * 4 + r;
                out[(size_t)row * N + col] = acc[mi][ni][r];
            }
    }
}

// ---------------------------------------------------------------------------
// Flash attention v9 (r10-exact — best measured config, 66.4 us):
// 128-row Q tile, 8 waves (512 thr), key-split. Waves 0-3 process keys
// [0,1024), waves 4-7 keys [1024,2048); each group has its own K/V LDS stage
// (2-MFMA-per-LDS-read reuse) at 2 blocks/CU = 16 waves/CU. Un-normalized
// softmax (p=2^s) => partials combine by plain addition in an LDS epilogue.
// The P LDS round-trip is LOAD-BEARING: it decouples softmax and PV phases
// so sibling waves overlap (r11's in-register P serialized the chain and
// REGRESSED 66->76us). setprio/perm-pack also regressed (r4). FROZEN.
// ---------------------------------------------------------------------------
__global__ __launch_bounds__(512) void attn_kernel(
    const unsigned short* __restrict__ qkv,
    unsigned short* __restrict__ ao)
{
    extern __shared__ char smem[];

    const int qt = blockIdx.x;          // 128-row query tile
    const int h  = blockIdx.y;
    const int b  = blockIdx.z;

    const int tid  = threadIdx.x;
    const int wave = tid >> 6;
    const int g    = wave >> 2;         // key-split group (0: keys lo, 1: hi)
    const int gw   = wave & 3;          // wave within group -> 32-row slice
    const int lane = tid & 63;
    const int quad = lane >> 4;
    const int l16  = lane & 15;
    const int gtid = tid & 255;         // thread within group (staging)

    short* Ks = (short*)smem + g * (64 * 72);            // [key][dim] swizzled
    short* Vt = (short*)(smem + 18432) + g * (64 * 72);  // [dim][pos] swizzled
    short* Ps = (short*)(smem + 36864) + wave * (32 * 72); // per-wave P

    bf16x8 qf[2][2];
#pragma unroll
    for (int mi = 0; mi < 2; mi++) {
        const int qrow = qt * 128 + gw * 32 + mi * 16 + l16;
        const unsigned short* qb = qkv + (size_t)(b * S_ + qrow) * 3072 + h * 192;
        qf[mi][0] = *reinterpret_cast<const bf16x8*>(qb + quad * 8);
        qf[mi][1] = *reinterpret_cast<const bf16x8*>(qb + 32 + quad * 8);
    }

    // all-ones B fragment for the l row-sum MFMA
    bf16x8 vones;
#pragma unroll
    for (int j = 0; j < 8; j++) vones[j] = (short)0x3F80;

    f32x4 o[2][4] = {};
    f32x4 o_l[2] = {};                // l accumulator (row sums of P)

    const int skey = gtid >> 3;       // 0..31 (K rows)
    const int soct = gtid & 7;        // 0..7  (dim octet)
    const int vp   = gtid >> 3;       // 0..31 (V key pair id)
    const int kA   = (vp & 15) + ((vp >> 4) << 5);
    const int kB   = kA + 16;
    const int posA = 4 * (vp & 15) + 2 * (vp >> 4);
    const int vwr  = ((posA >> 3) ^ soct) * 8 + (posA & 7);

    const int kb0   = g * (S_ / 2);
    const int kbend = kb0 + S_ / 2;

    const unsigned short* kbase0 = qkv + (size_t)(b * S_) * 3072 + h * 192 + 64;
    const unsigned short* vbase0 = qkv + (size_t)(b * S_) * 3072 + h * 192 + 128;

    bf16x8 pk0 = *reinterpret_cast<const bf16x8*>(kbase0 + (size_t)(kb0 + skey) * 3072 + soct * 8);
    bf16x8 pk1 = *reinterpret_cast<const bf16x8*>(kbase0 + (size_t)(kb0 + skey + 32) * 3072 + soct * 8);
    bf16x8 pv0 = *reinterpret_cast<const bf16x8*>(vbase0 + (size_t)(kb0 + kA) * 3072 + soct * 8);
    bf16x8 pv1 = *reinterpret_cast<const bf16x8*>(vbase0 + (size_t)(kb0 + kB) * 3072 + soct * 8);

    for (int kb = kb0; kb < kbend; kb += 64) {
        {
            const int woct0 = soct ^ ((skey >> 3) & 1);
            *reinterpret_cast<bf16x8*>(&Ks[skey * 72 + woct0 * 8]) = pk0;
            const int woct1 = soct ^ (((skey + 32) >> 3) & 1);
            *reinterpret_cast<bf16x8*>(&Ks[(skey + 32) * 72 + woct1 * 8]) = pk1;
#pragma unroll
            for (int j = 0; j < 8; j++) {
                const int d = soct * 8 + j;
                const unsigned int val =
                    (unsigned int)(unsigned short)pv0[j] |
                    ((unsigned int)(unsigned short)pv1[j] << 16);
                *reinterpret_cast<unsigned int*>(&Vt[d * 72 + vwr]) = val;
            }
        }
        __syncthreads();

        {
            const int kbn = (kb + 64 < kbend) ? kb + 64 : kb;
            pk0 = *reinterpret_cast<const bf16x8*>(
                kbase0 + (size_t)(kbn + skey) * 3072 + soct * 8);
            pk1 = *reinterpret_cast<const bf16x8*>(
                kbase0 + (size_t)(kbn + skey + 32) * 3072 + soct * 8);
            pv0 = *reinterpret_cast<const bf16x8*>(
                vbase0 + (size_t)(kbn + kA) * 3072 + soct * 8);
            pv1 = *reinterpret_cast<const bf16x8*>(
                vbase0 + (size_t)(kbn + kB) * 3072 + soct * 8);
        }

        // --- QK^T ---
        f32x4 s[2][4] = {};
#pragma unroll
        for (int c2 = 0; c2 < 2; c2++) {
#pragma unroll
            for (int nt = 0; nt < 4; nt++) {
                const int key = nt * 16 + l16;
                const int roct = (c2 * 4 + quad) ^ ((key >> 3) & 1);
                bf16x8 kf = *reinterpret_cast<const bf16x8*>(
                    &Ks[key * 72 + roct * 8]);
                s[0][nt] = __builtin_amdgcn_mfma_f32_16x16x32_bf16(qf[0][c2], kf, s[0][nt], 0, 0, 0);
                s[1][nt] = __builtin_amdgcn_mfma_f32_16x16x32_bf16(qf[1][c2], kf, s[1][nt], 0, 0, 0);
            }
        }

        // --- softmax: p = 2^s; packed cvt; b64 store at pos 4*l16 ---
#pragma unroll
        for (int mi = 0; mi < 2; mi++) {
#pragma unroll
            for (int r = 0; r < 4; r++) {
                const int m = mi * 16 + quad * 4 + r;
                const float p0 = exp2f(s[mi][0][r]);
                const float p1 = exp2f(s[mi][1][r]);
                const float p2 = exp2f(s[mi][2][r]);
                const float p3 = exp2f(s[mi][3][r]);
                uint2 w;
                w.x = pk2bf(p0, p1);
                w.y = pk2bf(p2, p3);
                *reinterpret_cast<uint2*>(&Ps[m * 72 + l16 * 4]) = w;
            }
        }

        // --- PV + l row-sum via ones MFMA ---
#pragma unroll
        for (int c2 = 0; c2 < 2; c2++) {
            bf16x8 pf[2];
#pragma unroll
            for (int mi = 0; mi < 2; mi++) {
                const int m = mi * 16 + l16;
                pf[mi] = *reinterpret_cast<const bf16x8*>(
                    &Ps[m * 72 + c2 * 32 + quad * 8]);
            }
#pragma unroll
            for (int ct = 0; ct < 4; ct++) {
                const int row = ct * 16 + l16;
                const int blk = (c2 * 4 + quad) ^ (row >> 3);
                bf16x8 vf = *reinterpret_cast<const bf16x8*>(
                    &Vt[row * 72 + blk * 8]);
                o[0][ct] = __builtin_amdgcn_mfma_f32_16x16x32_bf16(pf[0], vf, o[0][ct], 0, 0, 0);
                o[1][ct] = __builtin_amdgcn_mfma_f32_16x16x32_bf16(pf[1], vf, o[1][ct], 0, 0, 0);
            }
            o_l[0] = __builtin_amdgcn_mfma_f32_16x16x32_bf16(pf[0], vones, o_l[0], 0, 0, 0);
            o_l[1] = __builtin_amdgcn_mfma_f32_16x16x32_bf16(pf[1], vones, o_l[1], 0, 0, 0);
        }
        __syncthreads();
    }

    // --- key-split combine: group 1 parks partials in LDS (f32, exact), ---
    // --- group 0 adds, normalizes, stores.                              ---
    float* ex = (float*)smem;
    const int slot = (gw * 64 + lane) * 40;   // 32 o floats + 8 l floats
    if (g == 1) {
#pragma unroll
        for (int mi = 0; mi < 2; mi++) {
#pragma unroll
            for (int ct = 0; ct < 4; ct++)
                *reinterpret_cast<f32x4*>(&ex[slot + mi * 16 + ct * 4]) = o[mi][ct];
            *reinterpret_cast<f32x4*>(&ex[slot + 32 + mi * 4]) = o_l[mi];
        }
    }
    __syncthreads();
    if (g == 0) {
#pragma unroll
        for (int mi = 0; mi < 2; mi++) {
#pragma unroll
            for (int ct = 0; ct < 4; ct++) {
                f32x4 t = *reinterpret_cast<const f32x4*>(&ex[slot + mi * 16 + ct * 4]);
                o[mi][ct] += t;
            }
            f32x4 tl = *reinterpret_cast<const f32x4*>(&ex[slot + 32 + mi * 4]);
            o_l[mi] += tl;
        }
#pragma unroll
        for (int mi = 0; mi < 2; mi++) {
            f32x4 rl;
#pragma unroll
            for (int r = 0; r < 4; r++) rl[r] = 1.f / o_l[mi][r];
#pragma unroll
            for (int ct = 0; ct < 4; ct++)
#pragma unroll
                for (int r = 0; r < 4; r++) {
                    const int row = qt * 128 + gw * 32 + mi * 16 + quad * 4 + r;
                    ao[(size_t)(b * S_ + row) * D_ + h * HD_ + ct * 16 + l16] =
                        (unsigned short)f2bf(o[mi][ct][r] * rl[r]);
                }
        }
    }
}

// ---------------------------------------------------------------------------
// LN over D=1024 with fused partial-sum + bias + residual; packed stores.
// ---------------------------------------------------------------------------
template<int RESM, bool FLAG_OUT>
__global__ __launch_bounds__(256) void ln_sum_kernel(
    const float* __restrict__ p0,
    const float* __restrict__ p1,
    const float* __restrict__ bias,
    const unsigned short* __restrict__ resb,
    const float* __restrict__ resf,
    const float* __restrict__ g,
    const float* __restrict__ bt,
    const int* __restrict__ flags,
    void* __restrict__ out)
{
    const int row = blockIdx.x;
    const int tid = threadIdx.x;
    const int c0  = tid * 4;
    const size_t base = (size_t)row * D_ + c0;

    float4 a = *reinterpret_cast<const float4*>(p0 + base);
    float4 bq = *reinterpret_cast<const float4*>(p1 + base);
    float4 bi = *reinterpret_cast<const float4*>(bias + c0);

    float v[4] = {a.x + bq.x + bi.x, a.y + bq.y + bi.y,
                  a.z + bq.z + bi.z, a.w + bq.w + bi.w};

    if constexpr (RESM == 1) {
        if (flags[0]) {
            float4 rv = *reinterpret_cast<const float4*>(resf + base);
            v[0] += rv.x; v[1] += rv.y; v[2] += rv.z; v[3] += rv.w;
        } else {
            uint2 rv = *reinterpret_cast<const uint2*>(resb + base);
            v[0] += bf2f((unsigned short)(rv.x & 0xFFFF));
            v[1] += bf2f((unsigned short)(rv.x >> 16));
            v[2] += bf2f((unsigned short)(rv.y & 0xFFFF));
            v[3] += bf2f((unsigned short)(rv.y >> 16));
        }
    } else {
        uint2 rv = *reinterpret_cast<const uint2*>(resb + base);
        v[0] += bf2f((unsigned short)(rv.x & 0xFFFF));
        v[1] += bf2f((unsigned short)(rv.x >> 16));
        v[2] += bf2f((unsigned short)(rv.y & 0xFFFF));
        v[3] += bf2f((unsigned short)(rv.y >> 16));
    }

    float s = v[0] + v[1] + v[2] + v[3];
    float sq = v[0] * v[0] + v[1] * v[1] + v[2] * v[2] + v[3] * v[3];
#pragma unroll
    for (int msk = 1; msk < 64; msk <<= 1) {
        s += __shfl_xor(s, msk);
        sq += __shfl_xor(sq, msk);
    }
    __shared__ float ss[4], ssq[4];
    if ((tid & 63) == 0) { ss[tid >> 6] = s; ssq[tid >> 6] = sq; }
    __syncthreads();
    s = ss[0] + ss[1] + ss[2] + ss[3];
    sq = ssq[0] + ssq[1] + ssq[2] + ssq[3];

    const float mean = s * (1.f / D_);
    const float var = sq * (1.f / D_) - mean * mean;
    const float rinv = rsqrtf(var + EPS_);

    float w[4];
#pragma unroll
    for (int i = 0; i < 4; i++)
        w[i] = (v[i] - mean) * rinv * g[c0 + i] + bt[c0 + i];

    int outF32 = 0;
    if constexpr (FLAG_OUT) outF32 = flags[0];

    if (FLAG_OUT && outF32) {
        float4 o4 = {w[0], w[1], w[2], w[3]};
        *reinterpret_cast<float4*>((float*)out + base) = o4;
    } else {
        uint2 o2;
        o2.x = pk2bf(w[0], w[1]);
        o2.y = pk2bf(w[2], w[3]);
        *reinterpret_cast<uint2*>((unsigned short*)out + base) = o2;
    }
}

// ---------------------------------------------------------------------------
extern "C" void kernel_launch(void* const* d_in, const int* in_sizes, int n_in,
                              void* d_out, int out_size, void* d_ws, size_t ws_size,
                              hipStream_t stream) {
    char* ws = (char*)d_ws;

    int*            flags = (int*)(ws + 0);
    unsigned short* xb    = (unsigned short*)(ws + 256);
    unsigned short* wqkvT = (unsigned short*)(ws + 8388864);
    unsigned short* woT   = (unsigned short*)(ws + 14680320);
    unsigned short* w1T   = (unsigned short*)(ws + 16777472);
    unsigned short* w2T   = (unsigned short*)(ws + 25166080);
    float*          bof   = (float*)(ws + 33554688);
    float*          g1f   = (float*)(ws + 33558784);
    float*          bt1f  = (float*)(ws + 33562880);
    float*          b1f   = (float*)(ws + 33566976);
    float*          b2f   = (float*)(ws + 33583360);
    float*          g2f   = (float*)(ws + 33587456);
    float*          bt2f  = (float*)(ws + 33591552);
    unsigned short* qkv   = (unsigned short*)(ws + 33595648);
    unsigned short* ao    = (unsigned short*)(ws + 256);          // reuse xb
    unsigned short* y     = (unsigned short*)(ws + 33595648);     // reuse qkv
    unsigned short* hbuf  = (unsigned short*)(ws + 41984256);
    float*          part0 = (float*)(ws + 58761472);
    float*          part1 = (float*)(ws + 75538688);
    float*          hpart0= (float*)(ws + 256);                   // reuse ao slot

    dim3 blk(256);

    // allow >64KB dynamic LDS: attn 73728, 256^2 ring 131072; 128^2 rings 65536.
    static int attr_done = 0;
    if (!attr_done) {
        hipFuncSetAttribute(reinterpret_cast<const void*>(attn_kernel),
                            hipFuncAttributeMaxDynamicSharedMemorySize, 73728);
        hipFuncSetAttribute(
            reinterpret_cast<const void*>(&gemm256_kernel<true, true, false>),
            hipFuncAttributeMaxDynamicSharedMemorySize, 131072);
        hipFuncSetAttribute(
            reinterpret_cast<const void*>(&gemm128r_kernel<false, false, true>),
            hipFuncAttributeMaxDynamicSharedMemorySize, 65536);
        hipFuncSetAttribute(reinterpret_cast<const void*>(gemm128_sk_kernel),
                            hipFuncAttributeMaxDynamicSharedMemorySize, 65536);
        attr_done = 1;
    }

    DetectArgs da;
    for (int i = 0; i < 12; i++) {
        da.p[i] = (const unsigned short*)d_in[i];
        da.n[i] = in_sizes[i];
    }
    detect_kernel<<<dim3(12), blk, 0, stream>>>(da, flags);

    // x convert + small-vector converts (fused)
    VecArgs va;
    const int vidx[7] = {3, 4, 5, 7, 9, 10, 11};
    float* vdst[7] = {bof, g1f, bt1f, b1f, b2f, g2f, bt2f};
    for (int i = 0; i < 7; i++) {
        va.src[i] = d_in[vidx[i]];
        va.dst[i] = vdst[i];
        va.n[i]   = in_sizes[vidx[i]];
        va.fidx[i] = vidx[i];
    }
    conv_x_vecs_kernel<<<dim3((NT * D_ + 255) / 256), blk, 0, stream>>>(
        d_in[0], xb, NT * D_, va, flags);

    // 4 weight transposes (fused via z-sections)
    TArgs ta;
    ta.src[0] = d_in[1]; ta.dst[0] = wqkvT; ta.K[0] = D_;  ta.N[0] = 3 * D_; ta.fidx[0] = 1;
    ta.src[1] = d_in[2]; ta.dst[1] = woT;   ta.K[1] = D_;  ta.N[1] = D_;     ta.fidx[1] = 2;
    ta.src[2] = d_in[6]; ta.dst[2] = w1T;   ta.K[2] = D_;  ta.N[2] = FF_;    ta.fidx[2] = 6;
    ta.src[3] = d_in[8]; ta.dst[3] = w2T;   ta.K[3] = FF_; ta.N[3] = D_;     ta.fidx[3] = 8;
    ta.start[0] = 0;
    for (int wI = 0; wI < 4; wI++)
        ta.start[wI + 1] = ta.start[wI] + (ta.K[wI] / 32) * (ta.N[wI] / 32);
    conv_t_all_kernel<<<dim3(ta.start[4]), blk, 0, stream>>>(ta, flags);

    // 1) qkv = x @ w_qkv, Q part pre-scaled by KLOG2E (128^2 ring, r13-proven:
    //    grid 768 = full CU coverage at 2/CU)
    gemm128r_kernel<false, false, true>
        <<<dim3(NT / 128, 3072 / 128), blk, 65536, stream>>>(
            xb, wqkvT, nullptr, qkv, NT, 3072, 1024);

    // 2) attention -> ao bf16 (128-row tiles, 8-wave key-split blocks)
    attn_kernel<<<dim3(S_ / 128, H_, B_), dim3(512), 73728, stream>>>(qkv, ao);

    // 3) wo projection, split-K x2 ring pipeline -> raw f32 partials
    gemm128_sk_kernel<<<dim3(NT / 128, 1024 / 128, 2), blk, 65536, stream>>>(
        ao, woT, part0, part1, NT, 1024, 1024);

    // 4) y = LN(part0+part1 + b_o + x)
    ln_sum_kernel<1, false><<<dim3(NT), blk, 0, stream>>>(
        part0, part1, bof, (const unsigned short*)d_in[0], (const float*)d_in[0],
        g1f, bt1f, flags, y);

    // 5) h = relu(y @ w1 + b1) (256^2 ring, r13-proven: grid 256 = 1/CU exact;
    //    r14 showed 128^2 was worse here — no coverage deficit to fix)
    gemm256_kernel<true, true, false>
        <<<dim3(NT / 256, 4096 / 256), dim3(512), 131072, stream>>>(
            y, w1T, b1f, hbuf, NT, 4096, 1024);

    // 6) FFN2, split-K x2 ring pipeline -> raw f32 partials
    gemm128_sk_kernel<<<dim3(NT / 128, 1024 / 128, 2), blk, 65536, stream>>>(
        hbuf, w2T, hpart0, part1, NT, 1024, 4096);

    // 7) out = LN(hpart0+part1 + b2 + y), output dtype per flags[0]
    ln_sum_kernel<2, true><<<dim3(NT), blk, 0, stream>>>(
        hpart0, part1, b2f, y, nullptr, g2f, bt2f, flags, d_out);
}

// Round 16
// 362.273 us; speedup vs baseline: 1.0379x; 1.0379x over previous
//
#include <hip/hip_runtime.h>
#include <hip/hip_bf16.h>

// Shapes (fixed by the problem)
#define B_  2
#define S_  2048
#define D_  1024
#define H_  16
#define HD_ 64
#define FF_ 4096
#define NT  (B_ * S_)          // 4096 tokens
#define SCALE_ 0.125f          // 1/sqrt(64)
#define KLOG2E 0.1803368801111f // SCALE * log2(e)
#define EPS_  1e-5f

typedef __attribute__((ext_vector_type(8))) short bf16x8;   // 8 bf16 = 4 VGPRs
typedef __attribute__((ext_vector_type(4))) float f32x4;    // MFMA C/D frag

__device__ inline short f2bf(float f) {
    __hip_bfloat16 h = __float2bfloat16(f);
    return __builtin_bit_cast(short, h);
}
__device__ inline float bf2f(unsigned short u) {
    __hip_bfloat16 h = __builtin_bit_cast(__hip_bfloat16, u);
    return __bfloat162float(h);
}
// packed f32x2 -> bf16x2 (v_cvt_pk_bf16_f32 on gfx950), lo in low 16 bits.
// NOTE: __hip_bfloat162 is NOT trivially copyable -> bit-cast members.
__device__ inline unsigned int pk2bf(float lo, float hi) {
    __hip_bfloat162 h = __float22bfloat162_rn(float2{lo, hi});
    const unsigned short l16 = __builtin_bit_cast(unsigned short, h.x);
    const unsigned short h16 = __builtin_bit_cast(unsigned short, h.y);
    return (unsigned int)l16 | ((unsigned int)h16 << 16);
}

#define GLOBAL_AS __attribute__((address_space(1)))
#define LDS_AS    __attribute__((address_space(3)))

// ---------------------------------------------------------------------------
// Dtype detection (verified working)
// ---------------------------------------------------------------------------
struct DetectArgs { const unsigned short* p[12]; int n[12]; };

__global__ __launch_bounds__(256) void detect_kernel(DetectArgs a, int* flags) {
    const int t = blockIdx.x;
    const unsigned short* s = a.p[t];
    const int cnt = min(a.n[t], 16384);
    const int tid = threadIdx.x;
    int huge = 0, zeven = 0;
    for (int i = tid; i < cnt; i += 256) {
        const unsigned short v = s[i];
        const int e = (v >> 7) & 0xFF;
        if (e >= 142) huge++;
        if (((i & 1) == 0) && ((v & 0x7FFF) == 0)) zeven++;
    }
    __shared__ int sh, sz;
    if (tid == 0) { sh = 0; sz = 0; }
    __syncthreads();
    atomicAdd(&sh, huge);
    atomicAdd(&sz, zeven);
    __syncthreads();
    if (tid == 0) flags[t] = (sh > 0 || sz * 4 > cnt) ? 1 : 0;
}

// x convert -> bf16; block 0..6 also convert the 7 small f32 vectors
struct VecArgs { const void* src[7]; float* dst[7]; int n[7]; int fidx[7]; };

__global__ __launch_bounds__(256) void conv_x_vecs_kernel(
    const void* __restrict__ src, unsigned short* __restrict__ dst, int n,
    VecArgs a, const int* __restrict__ flags)
{
    const int i = blockIdx.x * 256 + threadIdx.x;
    if (i < n) {
        if (flags[0])
            dst[i] = (unsigned short)f2bf(((const float*)src)[i]);
        else
            dst[i] = ((const unsigned short*)src)[i];
    }
    if (blockIdx.x < 7) {
        const int v = blockIdx.x;
        const int f = flags[a.fidx[v]];
        for (int j = threadIdx.x; j < a.n[v]; j += 256) {
            a.dst[v][j] = f ? ((const float*)a.src[v])[j]
                            : bf2f(((const unsigned short*)a.src[v])[j]);
        }
    }
}

// fused tiled transpose convert for all 4 weights: src [K,N] -> dst [N,K] bf16
struct TArgs {
    const void* src[4]; unsigned short* dst[4];
    int K[4], N[4], fidx[4], start[5];
};

__global__ __launch_bounds__(256) void conv_t_all_kernel(
    TArgs t, const int* __restrict__ flags)
{
    __shared__ short T[32][33];
    const int tile = blockIdx.x;
    int w = 0;
    if (tile >= t.start[1]) w = 1;
    if (tile >= t.start[2]) w = 2;
    if (tile >= t.start[3]) w = 3;
    const int rel = tile - t.start[w];
    const int K = t.K[w], N = t.N[w];
    const int tilesN = N / 32;
    const int kt = (rel / tilesN) * 32, nt = (rel % tilesN) * 32;
    const void* src = t.src[w];
    unsigned short* dst = t.dst[w];
    const int f = flags[t.fidx[w]];

    const int c  = threadIdx.x & 31;
    const int r0 = (threadIdx.x >> 5) * 4;
#pragma unroll
    for (int i = 0; i < 4; i++) {
        const int r = r0 + i;
        const size_t gi = (size_t)(kt + r) * N + nt + c;
        short v = f ? f2bf(((const float*)src)[gi])
                    : (short)((const unsigned short*)src)[gi];
        T[c][r] = v;
    }
    __syncthreads();
#pragma unroll
    for (int i = 0; i < 4; i++) {
        const int n = r0 + i;
        dst[(size_t)(nt + n) * K + kt + c] = (unsigned short)T[n][c];
    }
}

// ---------------------------------------------------------------------------
// 256x256 MFMA GEMM, 8 waves (512 thr), BK=32, 4-slot LDS ring with COUNTED
// vmcnt pipeline (T3+T4) — r9 verified. Used for ffn1 (grid 256 = 1/CU full
// coverage; r14 A/B showed the 128^2 ring was ~7us WORSE for ffn1: its 256^2
// grid had no coverage deficit, so 128^2 only doubled B-panel staging).
// ---------------------------------------------------------------------------
#define G256_STAGE(tile_)                                                     \
    do {                                                                      \
        char* sb_ = smem + (size_t)((tile_) & 3) * 32768;                     \
        const int kb_ = (tile_) << 5;                                         \
        __builtin_amdgcn_global_load_lds(                                     \
            (const GLOBAL_AS void*)(ag0 + kb_),                               \
            (LDS_AS void*)(sb_ + sdst2), 16, 0, 0);                           \
        __builtin_amdgcn_global_load_lds(                                     \
            (const GLOBAL_AS void*)(ag1 + kb_),                               \
            (LDS_AS void*)(sb_ + 8192 + sdst2), 16, 0, 0);                    \
        __builtin_amdgcn_global_load_lds(                                     \
            (const GLOBAL_AS void*)(bg0 + kb_),                               \
            (LDS_AS void*)(sb_ + 16384 + sdst2), 16, 0, 0);                   \
        __builtin_amdgcn_global_load_lds(                                     \
            (const GLOBAL_AS void*)(bg1 + kb_),                               \
            (LDS_AS void*)(sb_ + 24576 + sdst2), 16, 0, 0);                   \
    } while (0)

template<bool HAS_BIAS, bool RELU, bool QSCALE>
__global__ __launch_bounds__(512) void gemm256_kernel(
    const unsigned short* __restrict__ A,
    const unsigned short* __restrict__ Bt,
    const float* __restrict__ bias,
    unsigned short* __restrict__ out,
    int M, int N, int K)
{
    extern __shared__ char smem[];

    const int tid  = threadIdx.x;
    const int wave = tid >> 6;
    const int lane = tid & 63;
    const int quad = lane >> 4;
    const int l16  = lane & 15;
    const int wr   = wave >> 2;      // 0..1 -> 128-row half
    const int wc   = wave & 3;       // 0..3 -> 64-col slice

    const int row0 = blockIdx.x * 256;
    const int col0 = blockIdx.y * 256;

    // staging map: thread -> (row srow, swizzled k-slot); LDS dest is
    // wave-uniform base + lane*16B (gload_lds requirement, verified).
    const int srow  = tid >> 2;                                   // 0..127
    const int sk    = (((tid & 3) ^ ((srow >> 1) & 3)) * 8);      // swizzled
    const int sdst2 = srow * 64 + (tid & 3) * 16;                 // bytes
    const unsigned short* ag0 = A  + (size_t)(row0 + srow) * K + sk;
    const unsigned short* ag1 = A  + (size_t)(row0 + 128 + srow) * K + sk;
    const unsigned short* bg0 = Bt + (size_t)(col0 + srow) * K + sk;
    const unsigned short* bg1 = Bt + (size_t)(col0 + 128 + srow) * K + sk;

    // read-side swizzled slot (same derivation as 128^2 kernel)
    const int rsw = (quad ^ ((l16 >> 1) & 3)) * 8;

    const int NTk = K >> 5;          // K-tiles of 32

    f32x4 acc[8][4] = {};

    // prologue: stage tiles 0,1,2
    G256_STAGE(0);
    G256_STAGE(1);
    G256_STAGE(2);

    for (int t = 0; t < NTk; t++) {
        if (t + 2 < NTk)
            asm volatile("s_waitcnt vmcnt(8)\n\ts_barrier" ::: "memory");
        else if (t + 1 < NTk)
            asm volatile("s_waitcnt vmcnt(4)\n\ts_barrier" ::: "memory");
        else
            asm volatile("s_waitcnt vmcnt(0)\n\ts_barrier" ::: "memory");

        const short* sA = (const short*)(smem + (size_t)(t & 3) * 32768);
        const short* sB = sA + 8192;

        bf16x8 af[8], bfr[4];
#pragma unroll
        for (int mi = 0; mi < 8; mi++)
            af[mi] = *reinterpret_cast<const bf16x8*>(
                &sA[(wr * 128 + mi * 16 + l16) * 32 + rsw]);
#pragma unroll
        for (int ni = 0; ni < 4; ni++)
            bfr[ni] = *reinterpret_cast<const bf16x8*>(
                &sB[(wc * 64 + ni * 16 + l16) * 32 + rsw]);
#pragma unroll
        for (int mi = 0; mi < 8; mi++)
#pragma unroll
            for (int ni = 0; ni < 4; ni++)
                acc[mi][ni] = __builtin_amdgcn_mfma_f32_16x16x32_bf16(
                    af[mi], bfr[ni], acc[mi][ni], 0, 0, 0);

        if (t + 3 < NTk) G256_STAGE(t + 3);
    }

#pragma unroll
    for (int ni = 0; ni < 4; ni++) {
        const int col = col0 + wc * 64 + ni * 16 + l16;
        float badd = 0.f;
        if constexpr (HAS_BIAS) badd = bias[col];
        float qs = 1.f;
        if constexpr (QSCALE)
            qs = (((col0 + wc * 64 + ni * 16) % 192) < 64) ? KLOG2E : 1.f;
#pragma unroll
        for (int mi = 0; mi < 8; mi++) {
#pragma unroll
            for (int r = 0; r < 4; r++) {
                const int row = row0 + wr * 128 + mi * 16 + quad * 4 + r;
                float v = acc[mi][ni][r] + badd;
                if constexpr (QSCALE) v *= qs;
                if constexpr (RELU) v = fmaxf(v, 0.f);
                out[(size_t)row * N + col] = (unsigned short)f2bf(v);
            }
        }
    }
}

// ---------------------------------------------------------------------------
// NON-SPLIT 128x128 ring GEMM (4 waves, BK=32, 4-slot x 16 KB = 64 KB LDS,
// counted vmcnt) with bias/QSCALE/RELU bf16 epilogue. Used for qkv only:
// grid 32x24 = 768 blocks = 100% CU coverage at 2/CU (the 256^2 ring gave
// only 192 blocks = 75% of CUs for qkv's shape). r13 verified: session best.
// ---------------------------------------------------------------------------
#define G128R_STAGE(tile_)                                                    \
    do {                                                                      \
        char* sb_ = smem + (size_t)((tile_) & 3) * 16384;                     \
        const int kb_ = (tile_) << 5;                                         \
        __builtin_amdgcn_global_load_lds(                                     \
            (const GLOBAL_AS void*)(agp0 + kb_),                              \
            (LDS_AS void*)(sb_ + adst0), 16, 0, 0);                           \
        __builtin_amdgcn_global_load_lds(                                     \
            (const GLOBAL_AS void*)(agp1 + kb_),                              \
            (LDS_AS void*)(sb_ + adst1), 16, 0, 0);                           \
        __builtin_amdgcn_global_load_lds(                                     \
            (const GLOBAL_AS void*)(bgp0 + kb_),                              \
            (LDS_AS void*)(sb_ + 8192 + adst0), 16, 0, 0);                    \
        __builtin_amdgcn_global_load_lds(                                     \
            (const GLOBAL_AS void*)(bgp1 + kb_),                              \
            (LDS_AS void*)(sb_ + 8192 + adst1), 16, 0, 0);                    \
    } while (0)

template<bool HAS_BIAS, bool RELU, bool QSCALE>
__global__ __launch_bounds__(256) void gemm128r_kernel(
    const unsigned short* __restrict__ A,
    const unsigned short* __restrict__ Bt,
    const float* __restrict__ bias,
    unsigned short* __restrict__ out,
    int M, int N, int K)
{
    extern __shared__ char smem[];

    const int tid  = threadIdx.x;
    const int wave = tid >> 6;
    const int lane = tid & 63;
    const int quad = lane >> 4;
    const int l16  = lane & 15;

    const int row0 = blockIdx.x * 128;
    const int col0 = blockIdx.y * 128;

    const int ldrow = lane >> 2;                                 // 0..15
    const int ldk   = (((lane & 3) ^ ((ldrow >> 1) & 3)) * 8);   // swizzled
    const unsigned short* agp0 = A  + (size_t)(row0 + wave * 32 + ldrow) * K + ldk;
    const unsigned short* agp1 = agp0 + (size_t)16 * K;
    const unsigned short* bgp0 = Bt + (size_t)(col0 + wave * 32 + ldrow) * K + ldk;
    const unsigned short* bgp1 = bgp0 + (size_t)16 * K;

    const int adst0 = (wave * 32 + ldrow) * 64 + (lane & 3) * 16;
    const int adst1 = adst0 + 16 * 64;

    const int wm = (wave >> 1) * 64;
    const int wn = (wave & 1) * 64;
    const int rsw = (quad ^ ((l16 >> 1) & 3)) * 8;

    const int NTk = K >> 5;          // K-tiles of 32

    f32x4 acc[4][4] = {};

    // prologue: stage tiles 0,1,2
    G128R_STAGE(0);
    if (1 < NTk) G128R_STAGE(1);
    if (2 < NTk) G128R_STAGE(2);

    for (int t = 0; t < NTk; t++) {
        if (t + 2 < NTk)
            asm volatile("s_waitcnt vmcnt(8)\n\ts_barrier" ::: "memory");
        else if (t + 1 < NTk)
            asm volatile("s_waitcnt vmcnt(4)\n\ts_barrier" ::: "memory");
        else
            asm volatile("s_waitcnt vmcnt(0)\n\ts_barrier" ::: "memory");

        const short* sA = (const short*)(smem + (size_t)(t & 3) * 16384);
        const short* sB = sA + 4096;

        bf16x8 af[4], bfr[4];
#pragma unroll
        for (int mi = 0; mi < 4; mi++)
            af[mi] = *reinterpret_cast<const bf16x8*>(
                &sA[(wm + mi * 16 + l16) * 32 + rsw]);
#pragma unroll
        for (int ni = 0; ni < 4; ni++)
            bfr[ni] = *reinterpret_cast<const bf16x8*>(
                &sB[(wn + ni * 16 + l16) * 32 + rsw]);
#pragma unroll
        for (int mi = 0; mi < 4; mi++)
#pragma unroll
            for (int ni = 0; ni < 4; ni++)
                acc[mi][ni] = __builtin_amdgcn_mfma_f32_16x16x32_bf16(
                    af[mi], bfr[ni], acc[mi][ni], 0, 0, 0);

        if (t + 3 < NTk) G128R_STAGE(t + 3);
    }

#pragma unroll
    for (int ni = 0; ni < 4; ni++) {
        const int col = col0 + wn + ni * 16 + l16;
        float badd = 0.f;
        if constexpr (HAS_BIAS) badd = bias[col];
        float qs = 1.f;
        if constexpr (QSCALE)
            qs = (((col0 + wn + ni * 16) % 192) < 64) ? KLOG2E : 1.f;
#pragma unroll
        for (int mi = 0; mi < 4; mi++) {
#pragma unroll
            for (int r = 0; r < 4; r++) {
                const int row = row0 + wm + mi * 16 + quad * 4 + r;
                float v = acc[mi][ni][r] + badd;
                if constexpr (QSCALE) v *= qs;
                if constexpr (RELU) v = fmaxf(v, 0.f);
                out[(size_t)row * N + col] = (unsigned short)f2bf(v);
            }
        }
    }
}

// ---------------------------------------------------------------------------
// Split-K 128x128 GEMM, BK=32, 4-slot LDS ring with COUNTED vmcnt pipeline —
// r10 verified. Raw f32 partials. Used for wo and ffn2.
// ---------------------------------------------------------------------------
#define GSK_STAGE(tile_)                                                      \
    do {                                                                      \
        char* sb_ = smem + (size_t)((tile_) & 3) * 16384;                     \
        const int kb_ = (tile_) << 5;                                         \
        __builtin_amdgcn_global_load_lds(                                     \
            (const GLOBAL_AS void*)(agp0 + kb_),                              \
            (LDS_AS void*)(sb_ + adst0), 16, 0, 0);                           \
        __builtin_amdgcn_global_load_lds(                                     \
            (const GLOBAL_AS void*)(agp1 + kb_),                              \
            (LDS_AS void*)(sb_ + adst1), 16, 0, 0);                           \
        __builtin_amdgcn_global_load_lds(                                     \
            (const GLOBAL_AS void*)(bgp0 + kb_),                              \
            (LDS_AS void*)(sb_ + 8192 + adst0), 16, 0, 0);                    \
        __builtin_amdgcn_global_load_lds(                                     \
            (const GLOBAL_AS void*)(bgp1 + kb_),                              \
            (LDS_AS void*)(sb_ + 8192 + adst1), 16, 0, 0);                    \
    } while (0)

__global__ __launch_bounds__(256) void gemm128_sk_kernel(
    const unsigned short* __restrict__ A,
    const unsigned short* __restrict__ Bt,
    float* __restrict__ out0,
    float* __restrict__ out1,
    int M, int N, int K)
{
    extern __shared__ char smem[];

    const int tid  = threadIdx.x;
    const int wave = tid >> 6;
    const int lane = tid & 63;
    const int quad = lane >> 4;
    const int l16  = lane & 15;

    const int row0 = blockIdx.x * 128;
    const int col0 = blockIdx.y * 128;
    const int z    = blockIdx.z;
    const int Kh   = K >> 1;

    const unsigned short* Az  = A  + (size_t)z * Kh;
    const unsigned short* Btz = Bt + (size_t)z * Kh;
    float* out = z ? out1 : out0;

    const int ldrow = lane >> 2;                                 // 0..15
    const int ldk   = (((lane & 3) ^ ((ldrow >> 1) & 3)) * 8);   // swizzled
    const unsigned short* agp0 = Az  + (size_t)(row0 + wave * 32 + ldrow) * K + ldk;
    const unsigned short* agp1 = agp0 + (size_t)16 * K;
    const unsigned short* bgp0 = Btz + (size_t)(col0 + wave * 32 + ldrow) * K + ldk;
    const unsigned short* bgp1 = bgp0 + (size_t)16 * K;

    // LDS byte destinations within a slot (A at 0, B at +8192):
    // row = wave*32+ldrow (+16), 64 B/row, slot (lane&3)*16.
    const int adst0 = (wave * 32 + ldrow) * 64 + (lane & 3) * 16;
    const int adst1 = adst0 + 16 * 64;

    const int wm = (wave >> 1) * 64;
    const int wn = (wave & 1) * 64;
    const int rsw = (quad ^ ((l16 >> 1) & 3)) * 8;

    const int NTk = Kh >> 5;         // K-tiles of 32

    f32x4 acc[4][4] = {};

    // prologue: stage tiles 0,1,2
    GSK_STAGE(0);
    if (1 < NTk) GSK_STAGE(1);
    if (2 < NTk) GSK_STAGE(2);

    for (int t = 0; t < NTk; t++) {
        if (t + 2 < NTk)
            asm volatile("s_waitcnt vmcnt(8)\n\ts_barrier" ::: "memory");
        else if (t + 1 < NTk)
            asm volatile("s_waitcnt vmcnt(4)\n\ts_barrier" ::: "memory");
        else
            asm volatile("s_waitcnt vmcnt(0)\n\ts_barrier" ::: "memory");

        const short* sA = (const short*)(smem + (size_t)(t & 3) * 16384);
        const short* sB = sA + 4096;

        bf16x8 af[4], bfr[4];
#pragma unroll
        for (int mi = 0; mi < 4; mi++)
            af[mi] = *reinterpret_cast<const bf16x8*>(
                &sA[(wm + mi * 16 + l16) * 32 + rsw]);
#pragma unroll
        for (int ni = 0; ni < 4; ni++)
            bfr[ni] = *reinterpret_cast<const bf16x8*>(
                &sB[(wn + ni * 16 + l16) * 32 + rsw]);
#pragma unroll
        for (int mi = 0; mi < 4; mi++)
#pragma unroll
            for (int ni = 0; ni < 4; ni++)
                acc[mi][ni] = __builtin_amdgcn_mfma_f32_16x16x32_bf16(
                    af[mi], bfr[ni], acc[mi][ni], 0, 0, 0);

        if (t + 3 < NTk) GSK_STAGE(t + 3);
    }

#pragma unroll
    for (int ni = 0; ni < 4; ni++) {
        const int col = col0 + wn + ni * 16 + l16;
#pragma unroll
        for (int mi = 0; mi < 4; mi++)
#pragma unroll
            for (int r = 0; r < 4; r++) {
                const int row = row0 + wm + mi * 16 + quad * 4 + r;
                out[(size_t)row * N + col] = acc[mi][ni][r];
            }
    }
}

// ---------------------------------------------------------------------------
// Flash attention v9 (r10-exact — best measured config, 66.4 us):
// 128-row Q tile, 8 waves (512 thr), key-split. Waves 0-3 process keys
// [0,1024), waves 4-7 keys [1024,2048); each group has its own K/V LDS stage
// (2-MFMA-per-LDS-read reuse) at 2 blocks/CU = 16 waves/CU. Un-normalized
// softmax (p=2^s) => partials combine by plain addition in an LDS epilogue.
// The P LDS round-trip is LOAD-BEARING: it decouples softmax and PV phases
// so sibling waves overlap (r11's in-register P serialized the chain and
// REGRESSED 66->76us). setprio/perm-pack also regressed (r4). FROZEN.
// ---------------------------------------------------------------------------
__global__ __launch_bounds__(512) void attn_kernel(
    const unsigned short* __restrict__ qkv,
    unsigned short* __restrict__ ao)
{
    extern __shared__ char smem[];

    const int qt = blockIdx.x;          // 128-row query tile
    const int h  = blockIdx.y;
    const int b  = blockIdx.z;

    const int tid  = threadIdx.x;
    const int wave = tid >> 6;
    const int g    = wave >> 2;         // key-split group (0: keys lo, 1: hi)
    const int gw   = wave & 3;          // wave within group -> 32-row slice
    const int lane = tid & 63;
    const int quad = lane >> 4;
    const int l16  = lane & 15;
    const int gtid = tid & 255;         // thread within group (staging)

    short* Ks = (short*)smem + g * (64 * 72);            // [key][dim] swizzled
    short* Vt = (short*)(smem + 18432) + g * (64 * 72);  // [dim][pos] swizzled
    short* Ps = (short*)(smem + 36864) + wave * (32 * 72); // per-wave P

    bf16x8 qf[2][2];
#pragma unroll
    for (int mi = 0; mi < 2; mi++) {
        const int qrow = qt * 128 + gw * 32 + mi * 16 + l16;
        const unsigned short* qb = qkv + (size_t)(b * S_ + qrow) * 3072 + h * 192;
        qf[mi][0] = *reinterpret_cast<const bf16x8*>(qb + quad * 8);
        qf[mi][1] = *reinterpret_cast<const bf16x8*>(qb + 32 + quad * 8);
    }

    // all-ones B fragment for the l row-sum MFMA
    bf16x8 vones;
#pragma unroll
    for (int j = 0; j < 8; j++) vones[j] = (short)0x3F80;

    f32x4 o[2][4] = {};
    f32x4 o_l[2] = {};                // l accumulator (row sums of P)

    const int skey = gtid >> 3;       // 0..31 (K rows)
    const int soct = gtid & 7;        // 0..7  (dim octet)
    const int vp   = gtid >> 3;       // 0..31 (V key pair id)
    const int kA   = (vp & 15) + ((vp >> 4) << 5);
    const int kB   = kA + 16;
    const int posA = 4 * (vp & 15) + 2 * (vp >> 4);
    const int vwr  = ((posA >> 3) ^ soct) * 8 + (posA & 7);

    const int kb0   = g * (S_ / 2);
    const int kbend = kb0 + S_ / 2;

    const unsigned short* kbase0 = qkv + (size_t)(b * S_) * 3072 + h * 192 + 64;
    const unsigned short* vbase0 = qkv + (size_t)(b * S_) * 3072 + h * 192 + 128;

    bf16x8 pk0 = *reinterpret_cast<const bf16x8*>(kbase0 + (size_t)(kb0 + skey) * 3072 + soct * 8);
    bf16x8 pk1 = *reinterpret_cast<const bf16x8*>(kbase0 + (size_t)(kb0 + skey + 32) * 3072 + soct * 8);
    bf16x8 pv0 = *reinterpret_cast<const bf16x8*>(vbase0 + (size_t)(kb0 + kA) * 3072 + soct * 8);
    bf16x8 pv1 = *reinterpret_cast<const bf16x8*>(vbase0 + (size_t)(kb0 + kB) * 3072 + soct * 8);

    for (int kb = kb0; kb < kbend; kb += 64) {
        {
            const int woct0 = soct ^ ((skey >> 3) & 1);
            *reinterpret_cast<bf16x8*>(&Ks[skey * 72 + woct0 * 8]) = pk0;
            const int woct1 = soct ^ (((skey + 32) >> 3) & 1);
            *reinterpret_cast<bf16x8*>(&Ks[(skey + 32) * 72 + woct1 * 8]) = pk1;
#pragma unroll
            for (int j = 0; j < 8; j++) {
                const int d = soct * 8 + j;
                const unsigned int val =
                    (unsigned int)(unsigned short)pv0[j] |
                    ((unsigned int)(unsigned short)pv1[j] << 16);
                *reinterpret_cast<unsigned int*>(&Vt[d * 72 + vwr]) = val;
            }
        }
        __syncthreads();

        {
            const int kbn = (kb + 64 < kbend) ? kb + 64 : kb;
            pk0 = *reinterpret_cast<const bf16x8*>(
                kbase0 + (size_t)(kbn + skey) * 3072 + soct * 8);
            pk1 = *reinterpret_cast<const bf16x8*>(
                kbase0 + (size_t)(kbn + skey + 32) * 3072 + soct * 8);
            pv0 = *reinterpret_cast<const bf16x8*>(
                vbase0 + (size_t)(kbn + kA) * 3072 + soct * 8);
            pv1 = *reinterpret_cast<const bf16x8*>(
                vbase0 + (size_t)(kbn + kB) * 3072 + soct * 8);
        }

        // --- QK^T ---
        f32x4 s[2][4] = {};
#pragma unroll
        for (int c2 = 0; c2 < 2; c2++) {
#pragma unroll
            for (int nt = 0; nt < 4; nt++) {
                const int key = nt * 16 + l16;
                const int roct = (c2 * 4 + quad) ^ ((key >> 3) & 1);
                bf16x8 kf = *reinterpret_cast<const bf16x8*>(
                    &Ks[key * 72 + roct * 8]);
                s[0][nt] = __builtin_amdgcn_mfma_f32_16x16x32_bf16(qf[0][c2], kf, s[0][nt], 0, 0, 0);
                s[1][nt] = __builtin_amdgcn_mfma_f32_16x16x32_bf16(qf[1][c2], kf, s[1][nt], 0, 0, 0);
            }
        }

        // --- softmax: p = 2^s; packed cvt; b64 store at pos 4*l16 ---
#pragma unroll
        for (int mi = 0; mi < 2; mi++) {
#pragma unroll
            for (int r = 0; r < 4; r++) {
                const int m = mi * 16 + quad * 4 + r;
                const float p0 = exp2f(s[mi][0][r]);
                const float p1 = exp2f(s[mi][1][r]);
                const float p2 = exp2f(s[mi][2][r]);
                const float p3 = exp2f(s[mi][3][r]);
                uint2 w;
                w.x = pk2bf(p0, p1);
                w.y = pk2bf(p2, p3);
                *reinterpret_cast<uint2*>(&Ps[m * 72 + l16 * 4]) = w;
            }
        }

        // --- PV + l row-sum via ones MFMA ---
#pragma unroll
        for (int c2 = 0; c2 < 2; c2++) {
            bf16x8 pf[2];
#pragma unroll
            for (int mi = 0; mi < 2; mi++) {
                const int m = mi * 16 + l16;
                pf[mi] = *reinterpret_cast<const bf16x8*>(
                    &Ps[m * 72 + c2 * 32 + quad * 8]);
            }
#pragma unroll
            for (int ct = 0; ct < 4; ct++) {
                const int row = ct * 16 + l16;
                const int blk = (c2 * 4 + quad) ^ (row >> 3);
                bf16x8 vf = *reinterpret_cast<const bf16x8*>(
                    &Vt[row * 72 + blk * 8]);
                o[0][ct] = __builtin_amdgcn_mfma_f32_16x16x32_bf16(pf[0], vf, o[0][ct], 0, 0, 0);
                o[1][ct] = __builtin_amdgcn_mfma_f32_16x16x32_bf16(pf[1], vf, o[1][ct], 0, 0, 0);
            }
            o_l[0] = __builtin_amdgcn_mfma_f32_16x16x32_bf16(pf[0], vones, o_l[0], 0, 0, 0);
            o_l[1] = __builtin_amdgcn_mfma_f32_16x16x32_bf16(pf[1], vones, o_l[1], 0, 0, 0);
        }
        __syncthreads();
    }

    // --- key-split combine: group 1 parks partials in LDS (f32, exact), ---
    // --- group 0 adds, normalizes, stores.                              ---
    float* ex = (float*)smem;
    const int slot = (gw * 64 + lane) * 40;   // 32 o floats + 8 l floats
    if (g == 1) {
#pragma unroll
        for (int mi = 0; mi < 2; mi++) {
#pragma unroll
            for (int ct = 0; ct < 4; ct++)
                *reinterpret_cast<f32x4*>(&ex[slot + mi * 16 + ct * 4]) = o[mi][ct];
            *reinterpret_cast<f32x4*>(&ex[slot + 32 + mi * 4]) = o_l[mi];
        }
    }
    __syncthreads();
    if (g == 0) {
#pragma unroll
        for (int mi = 0; mi < 2; mi++) {
#pragma unroll
            for (int ct = 0; ct < 4; ct++) {
                f32x4 t = *reinterpret_cast<const f32x4*>(&ex[slot + mi * 16 + ct * 4]);
                o[mi][ct] += t;
            }
            f32x4 tl = *reinterpret_cast<const f32x4*>(&ex[slot + 32 + mi * 4]);
            o_l[mi] += tl;
        }
#pragma unroll
        for (int mi = 0; mi < 2; mi++) {
            f32x4 rl;
#pragma unroll
            for (int r = 0; r < 4; r++) rl[r] = 1.f / o_l[mi][r];
#pragma unroll
            for (int ct = 0; ct < 4; ct++)
#pragma unroll
                for (int r = 0; r < 4; r++) {
                    const int row = qt * 128 + gw * 32 + mi * 16 + quad * 4 + r;
                    ao[(size_t)(b * S_ + row) * D_ + h * HD_ + ct * 16 + l16] =
                        (unsigned short)f2bf(o[mi][ct][r] * rl[r]);
                }
        }
    }
}

// ---------------------------------------------------------------------------
// LN over D=1024 with fused partial-sum + bias + residual; packed stores.
// ---------------------------------------------------------------------------
template<int RESM, bool FLAG_OUT>
__global__ __launch_bounds__(256) void ln_sum_kernel(
    const float* __restrict__ p0,
    const float* __restrict__ p1,
    const float* __restrict__ bias,
    const unsigned short* __restrict__ resb,
    const float* __restrict__ resf,
    const float* __restrict__ g,
    const float* __restrict__ bt,
    const int* __restrict__ flags,
    void* __restrict__ out)
{
    const int row = blockIdx.x;
    const int tid = threadIdx.x;
    const int c0  = tid * 4;
    const size_t base = (size_t)row * D_ + c0;

    float4 a = *reinterpret_cast<const float4*>(p0 + base);
    float4 bq = *reinterpret_cast<const float4*>(p1 + base);
    float4 bi = *reinterpret_cast<const float4*>(bias + c0);

    float v[4] = {a.x + bq.x + bi.x, a.y + bq.y + bi.y,
                  a.z + bq.z + bi.z, a.w + bq.w + bi.w};

    if constexpr (RESM == 1) {
        if (flags[0]) {
            float4 rv = *reinterpret_cast<const float4*>(resf + base);
            v[0] += rv.x; v[1] += rv.y; v[2] += rv.z; v[3] += rv.w;
        } else {
            uint2 rv = *reinterpret_cast<const uint2*>(resb + base);
            v[0] += bf2f((unsigned short)(rv.x & 0xFFFF));
            v[1] += bf2f((unsigned short)(rv.x >> 16));
            v[2] += bf2f((unsigned short)(rv.y & 0xFFFF));
            v[3] += bf2f((unsigned short)(rv.y >> 16));
        }
    } else {
        uint2 rv = *reinterpret_cast<const uint2*>(resb + base);
        v[0] += bf2f((unsigned short)(rv.x & 0xFFFF));
        v[1] += bf2f((unsigned short)(rv.x >> 16));
        v[2] += bf2f((unsigned short)(rv.y & 0xFFFF));
        v[3] += bf2f((unsigned short)(rv.y >> 16));
    }

    float s = v[0] + v[1] + v[2] + v[3];
    float sq = v[0] * v[0] + v[1] * v[1] + v[2] * v[2] + v[3] * v[3];
#pragma unroll
    for (int msk = 1; msk < 64; msk <<= 1) {
        s += __shfl_xor(s, msk);
        sq += __shfl_xor(sq, msk);
    }
    __shared__ float ss[4], ssq[4];
    if ((tid & 63) == 0) { ss[tid >> 6] = s; ssq[tid >> 6] = sq; }
    __syncthreads();
    s = ss[0] + ss[1] + ss[2] + ss[3];
    sq = ssq[0] + ssq[1] + ssq[2] + ssq[3];

    const float mean = s * (1.f / D_);
    const float var = sq * (1.f / D_) - mean * mean;
    const float rinv = rsqrtf(var + EPS_);

    float w[4];
#pragma unroll
    for (int i = 0; i < 4; i++)
        w[i] = (v[i] - mean) * rinv * g[c0 + i] + bt[c0 + i];

    int outF32 = 0;
    if constexpr (FLAG_OUT) outF32 = flags[0];

    if (FLAG_OUT && outF32) {
        float4 o4 = {w[0], w[1], w[2], w[3]};
        *reinterpret_cast<float4*>((float*)out + base) = o4;
    } else {
        uint2 o2;
        o2.x = pk2bf(w[0], w[1]);
        o2.y = pk2bf(w[2], w[3]);
        *reinterpret_cast<uint2*>((unsigned short*)out + base) = o2;
    }
}

// ---------------------------------------------------------------------------
extern "C" void kernel_launch(void* const* d_in, const int* in_sizes, int n_in,
                              void* d_out, int out_size, void* d_ws, size_t ws_size,
                              hipStream_t stream) {
    char* ws = (char*)d_ws;

    int*            flags = (int*)(ws + 0);
    unsigned short* xb    = (unsigned short*)(ws + 256);
    unsigned short* wqkvT = (unsigned short*)(ws + 8388864);
    unsigned short* woT   = (unsigned short*)(ws + 14680320);
    unsigned short* w1T   = (unsigned short*)(ws + 16777472);
    unsigned short* w2T   = (unsigned short*)(ws + 25166080);
    float*          bof   = (float*)(ws + 33554688);
    float*          g1f   = (float*)(ws + 33558784);
    float*          bt1f  = (float*)(ws + 33562880);
    float*          b1f   = (float*)(ws + 33566976);
    float*          b2f   = (float*)(ws + 33583360);
    float*          g2f   = (float*)(ws + 33587456);
    float*          bt2f  = (float*)(ws + 33591552);
    unsigned short* qkv   = (unsigned short*)(ws + 33595648);
    unsigned short* ao    = (unsigned short*)(ws + 256);          // reuse xb
    unsigned short* y     = (unsigned short*)(ws + 33595648);     // reuse qkv
    unsigned short* hbuf  = (unsigned short*)(ws + 41984256);
    float*          part0 = (float*)(ws + 58761472);
    float*          part1 = (float*)(ws + 75538688);
    float*          hpart0= (float*)(ws + 256);                   // reuse ao slot

    dim3 blk(256);

    // allow >64KB dynamic LDS: attn 73728, 256^2 ring 131072; 128^2 rings 65536.
    static int attr_done = 0;
    if (!attr_done) {
        hipFuncSetAttribute(reinterpret_cast<const void*>(attn_kernel),
                            hipFuncAttributeMaxDynamicSharedMemorySize, 73728);
        hipFuncSetAttribute(
            reinterpret_cast<const void*>(&gemm256_kernel<true, true, false>),
            hipFuncAttributeMaxDynamicSharedMemorySize, 131072);
        hipFuncSetAttribute(
            reinterpret_cast<const void*>(&gemm128r_kernel<false, false, true>),
            hipFuncAttributeMaxDynamicSharedMemorySize, 65536);
        hipFuncSetAttribute(reinterpret_cast<const void*>(gemm128_sk_kernel),
                            hipFuncAttributeMaxDynamicSharedMemorySize, 65536);
        attr_done = 1;
    }

    DetectArgs da;
    for (int i = 0; i < 12; i++) {
        da.p[i] = (const unsigned short*)d_in[i];
        da.n[i] = in_sizes[i];
    }
    detect_kernel<<<dim3(12), blk, 0, stream>>>(da, flags);

    // x convert + small-vector converts (fused)
    VecArgs va;
    const int vidx[7] = {3, 4, 5, 7, 9, 10, 11};
    float* vdst[7] = {bof, g1f, bt1f, b1f, b2f, g2f, bt2f};
    for (int i = 0; i < 7; i++) {
        va.src[i] = d_in[vidx[i]];
        va.dst[i] = vdst[i];
        va.n[i]   = in_sizes[vidx[i]];
        va.fidx[i] = vidx[i];
    }
    conv_x_vecs_kernel<<<dim3((NT * D_ + 255) / 256), blk, 0, stream>>>(
        d_in[0], xb, NT * D_, va, flags);

    // 4 weight transposes (fused via z-sections)
    TArgs ta;
    ta.src[0] = d_in[1]; ta.dst[0] = wqkvT; ta.K[0] = D_;  ta.N[0] = 3 * D_; ta.fidx[0] = 1;
    ta.src[1] = d_in[2]; ta.dst[1] = woT;   ta.K[1] = D_;  ta.N[1] = D_;     ta.fidx[1] = 2;
    ta.src[2] = d_in[6]; ta.dst[2] = w1T;   ta.K[2] = D_;  ta.N[2] = FF_;    ta.fidx[2] = 6;
    ta.src[3] = d_in[8]; ta.dst[3] = w2T;   ta.K[3] = FF_; ta.N[3] = D_;     ta.fidx[3] = 8;
    ta.start[0] = 0;
    for (int wI = 0; wI < 4; wI++)
        ta.start[wI + 1] = ta.start[wI] + (ta.K[wI] / 32) * (ta.N[wI] / 32);
    conv_t_all_kernel<<<dim3(ta.start[4]), blk, 0, stream>>>(ta, flags);

    // 1) qkv = x @ w_qkv, Q part pre-scaled by KLOG2E (128^2 ring, r13-proven:
    //    grid 768 = full CU coverage at 2/CU)
    gemm128r_kernel<false, false, true>
        <<<dim3(NT / 128, 3072 / 128), blk, 65536, stream>>>(
            xb, wqkvT, nullptr, qkv, NT, 3072, 1024);

    // 2) attention -> ao bf16 (128-row tiles, 8-wave key-split blocks)
    attn_kernel<<<dim3(S_ / 128, H_, B_), dim3(512), 73728, stream>>>(qkv, ao);

    // 3) wo projection, split-K x2 ring pipeline -> raw f32 partials
    gemm128_sk_kernel<<<dim3(NT / 128, 1024 / 128, 2), blk, 65536, stream>>>(
        ao, woT, part0, part1, NT, 1024, 1024);

    // 4) y = LN(part0+part1 + b_o + x)
    ln_sum_kernel<1, false><<<dim3(NT), blk, 0, stream>>>(
        part0, part1, bof, (const unsigned short*)d_in[0], (const float*)d_in[0],
        g1f, bt1f, flags, y);

    // 5) h = relu(y @ w1 + b1) (256^2 ring, r13-proven: grid 256 = 1/CU exact;
    //    r14 showed 128^2 was worse here — no coverage deficit to fix)
    gemm256_kernel<true, true, false>
        <<<dim3(NT / 256, 4096 / 256), dim3(512), 131072, stream>>>(
            y, w1T, b1f, hbuf, NT, 4096, 1024);

    // 6) FFN2, split-K x2 ring pipeline -> raw f32 partials
    gemm128_sk_kernel<<<dim3(NT / 128, 1024 / 128, 2), blk, 65536, stream>>>(
        hbuf, w2T, hpart0, part1, NT, 1024, 4096);

    // 7) out = LN(hpart0+part1 + b2 + y), output dtype per flags[0]
    ln_sum_kernel<2, true><<<dim3(NT), blk, 0, stream>>>(
        hpart0, part1, b2f, y, nullptr, g2f, bt2f, flags, d_out);
}

// Round 17
// 360.090 us; speedup vs baseline: 1.0442x; 1.0061x over previous
//
#include <hip/hip_runtime.h>
#include <hip/hip_bf16.h>

// Shapes (fixed by the problem)
#define B_  2
#define S_  2048
#define D_  1024
#define H_  16
#define HD_ 64
#define FF_ 4096
#define NT  (B_ * S_)          // 4096 tokens
#define SCALE_ 0.125f          // 1/sqrt(64)
#define KLOG2E 0.1803368801111f // SCALE * log2(e)
#define EPS_  1e-5f

typedef __attribute__((ext_vector_type(8))) short bf16x8;   // 8 bf16 = 4 VGPRs
typedef __attribute__((ext_vector_type(4))) float f32x4;    // MFMA C/D frag

__device__ inline short f2bf(float f) {
    __hip_bfloat16 h = __float2bfloat16(f);
    return __builtin_bit_cast(short, h);
}
__device__ inline float bf2f(unsigned short u) {
    __hip_bfloat16 h = __builtin_bit_cast(__hip_bfloat16, u);
    return __bfloat162float(h);
}
// packed f32x2 -> bf16x2 (v_cvt_pk_bf16_f32 on gfx950), lo in low 16 bits.
// NOTE: __hip_bfloat162 is NOT trivially copyable -> bit-cast members.
__device__ inline unsigned int pk2bf(float lo, float hi) {
    __hip_bfloat162 h = __float22bfloat162_rn(float2{lo, hi});
    const unsigned short l16 = __builtin_bit_cast(unsigned short, h.x);
    const unsigned short h16 = __builtin_bit_cast(unsigned short, h.y);
    return (unsigned int)l16 | ((unsigned int)h16 << 16);
}

#define GLOBAL_AS __attribute__((address_space(1)))
#define LDS_AS    __attribute__((address_space(3)))

// ---------------------------------------------------------------------------
// Dtype detection (verified working)
// ---------------------------------------------------------------------------
struct DetectArgs { const unsigned short* p[12]; int n[12]; };

__global__ __launch_bounds__(256) void detect_kernel(DetectArgs a, int* flags) {
    const int t = blockIdx.x;
    const unsigned short* s = a.p[t];
    const int cnt = min(a.n[t], 16384);
    const int tid = threadIdx.x;
    int huge = 0, zeven = 0;
    for (int i = tid; i < cnt; i += 256) {
        const unsigned short v = s[i];
        const int e = (v >> 7) & 0xFF;
        if (e >= 142) huge++;
        if (((i & 1) == 0) && ((v & 0x7FFF) == 0)) zeven++;
    }
    __shared__ int sh, sz;
    if (tid == 0) { sh = 0; sz = 0; }
    __syncthreads();
    atomicAdd(&sh, huge);
    atomicAdd(&sz, zeven);
    __syncthreads();
    if (tid == 0) flags[t] = (sh > 0 || sz * 4 > cnt) ? 1 : 0;
}

// x convert -> bf16; block 0..6 also convert the 7 small f32 vectors
struct VecArgs { const void* src[7]; float* dst[7]; int n[7]; int fidx[7]; };

__global__ __launch_bounds__(256) void conv_x_vecs_kernel(
    const void* __restrict__ src, unsigned short* __restrict__ dst, int n,
    VecArgs a, const int* __restrict__ flags)
{
    const int i = blockIdx.x * 256 + threadIdx.x;
    if (i < n) {
        if (flags[0])
            dst[i] = (unsigned short)f2bf(((const float*)src)[i]);
        else
            dst[i] = ((const unsigned short*)src)[i];
    }
    if (blockIdx.x < 7) {
        const int v = blockIdx.x;
        const int f = flags[a.fidx[v]];
        for (int j = threadIdx.x; j < a.n[v]; j += 256) {
            a.dst[v][j] = f ? ((const float*)a.src[v])[j]
                            : bf2f(((const unsigned short*)a.src[v])[j]);
        }
    }
}

// fused tiled transpose convert for all 4 weights: src [K,N] -> dst [N,K] bf16
struct TArgs {
    const void* src[4]; unsigned short* dst[4];
    int K[4], N[4], fidx[4], start[5];
};

__global__ __launch_bounds__(256) void conv_t_all_kernel(
    TArgs t, const int* __restrict__ flags)
{
    __shared__ short T[32][33];
    const int tile = blockIdx.x;
    int w = 0;
    if (tile >= t.start[1]) w = 1;
    if (tile >= t.start[2]) w = 2;
    if (tile >= t.start[3]) w = 3;
    const int rel = tile - t.start[w];
    const int K = t.K[w], N = t.N[w];
    const int tilesN = N / 32;
    const int kt = (rel / tilesN) * 32, nt = (rel % tilesN) * 32;
    const void* src = t.src[w];
    unsigned short* dst = t.dst[w];
    const int f = flags[t.fidx[w]];

    const int c  = threadIdx.x & 31;
    const int r0 = (threadIdx.x >> 5) * 4;
#pragma unroll
    for (int i = 0; i < 4; i++) {
        const int r = r0 + i;
        const size_t gi = (size_t)(kt + r) * N + nt + c;
        short v = f ? f2bf(((const float*)src)[gi])
                    : (short)((const unsigned short*)src)[gi];
        T[c][r] = v;
    }
    __syncthreads();
#pragma unroll
    for (int i = 0; i < 4; i++) {
        const int n = r0 + i;
        dst[(size_t)(nt + n) * K + kt + c] = (unsigned short)T[n][c];
    }
}

// ---------------------------------------------------------------------------
// 256x256 MFMA GEMM, 8 waves (512 thr), BK=32, 4-slot LDS ring with COUNTED
// vmcnt pipeline (T3+T4) — r9 verified. Used for ffn1 (grid 256 = 1/CU full
// coverage; r14 A/B showed the 128^2 ring was ~7us WORSE for ffn1: its 256^2
// grid had no coverage deficit, so 128^2 only doubled B-panel staging).
// ---------------------------------------------------------------------------
#define G256_STAGE(tile_)                                                     \
    do {                                                                      \
        char* sb_ = smem + (size_t)((tile_) & 3) * 32768;                     \
        const int kb_ = (tile_) << 5;                                         \
        __builtin_amdgcn_global_load_lds(                                     \
            (const GLOBAL_AS void*)(ag0 + kb_),                               \
            (LDS_AS void*)(sb_ + sdst2), 16, 0, 0);                           \
        __builtin_amdgcn_global_load_lds(                                     \
            (const GLOBAL_AS void*)(ag1 + kb_),                               \
            (LDS_AS void*)(sb_ + 8192 + sdst2), 16, 0, 0);                    \
        __builtin_amdgcn_global_load_lds(                                     \
            (const GLOBAL_AS void*)(bg0 + kb_),                               \
            (LDS_AS void*)(sb_ + 16384 + sdst2), 16, 0, 0);                   \
        __builtin_amdgcn_global_load_lds(                                     \
            (const GLOBAL_AS void*)(bg1 + kb_),                               \
            (LDS_AS void*)(sb_ + 24576 + sdst2), 16, 0, 0);                   \
    } while (0)

template<bool HAS_BIAS, bool RELU, bool QSCALE>
__global__ __launch_bounds__(512) void gemm256_kernel(
    const unsigned short* __restrict__ A,
    const unsigned short* __restrict__ Bt,
    const float* __restrict__ bias,
    unsigned short* __restrict__ out,
    int M, int N, int K)
{
    extern __shared__ char smem[];

    const int tid  = threadIdx.x;
    const int wave = tid >> 6;
    const int lane = tid & 63;
    const int quad = lane >> 4;
    const int l16  = lane & 15;
    const int wr   = wave >> 2;      // 0..1 -> 128-row half
    const int wc   = wave & 3;       // 0..3 -> 64-col slice

    const int row0 = blockIdx.x * 256;
    const int col0 = blockIdx.y * 256;

    // staging map: thread -> (row srow, swizzled k-slot); LDS dest is
    // wave-uniform base + lane*16B (gload_lds requirement, verified).
    const int srow  = tid >> 2;                                   // 0..127
    const int sk    = (((tid & 3) ^ ((srow >> 1) & 3)) * 8);      // swizzled
    const int sdst2 = srow * 64 + (tid & 3) * 16;                 // bytes
    const unsigned short* ag0 = A  + (size_t)(row0 + srow) * K + sk;
    const unsigned short* ag1 = A  + (size_t)(row0 + 128 + srow) * K + sk;
    const unsigned short* bg0 = Bt + (size_t)(col0 + srow) * K + sk;
    const unsigned short* bg1 = Bt + (size_t)(col0 + 128 + srow) * K + sk;

    // read-side swizzled slot (same derivation as 128^2 kernel)
    const int rsw = (quad ^ ((l16 >> 1) & 3)) * 8;

    const int NTk = K >> 5;          // K-tiles of 32

    f32x4 acc[8][4] = {};

    // prologue: stage tiles 0,1,2
    G256_STAGE(0);
    G256_STAGE(1);
    G256_STAGE(2);

    for (int t = 0; t < NTk; t++) {
        if (t + 2 < NTk)
            asm volatile("s_waitcnt vmcnt(8)\n\ts_barrier" ::: "memory");
        else if (t + 1 < NTk)
            asm volatile("s_waitcnt vmcnt(4)\n\ts_barrier" ::: "memory");
        else
            asm volatile("s_waitcnt vmcnt(0)\n\ts_barrier" ::: "memory");

        const short* sA = (const short*)(smem + (size_t)(t & 3) * 32768);
        const short* sB = sA + 8192;

        bf16x8 af[8], bfr[4];
#pragma unroll
        for (int mi = 0; mi < 8; mi++)
            af[mi] = *reinterpret_cast<const bf16x8*>(
                &sA[(wr * 128 + mi * 16 + l16) * 32 + rsw]);
#pragma unroll
        for (int ni = 0; ni < 4; ni++)
            bfr[ni] = *reinterpret_cast<const bf16x8*>(
                &sB[(wc * 64 + ni * 16 + l16) * 32 + rsw]);
#pragma unroll
        for (int mi = 0; mi < 8; mi++)
#pragma unroll
            for (int ni = 0; ni < 4; ni++)
                acc[mi][ni] = __builtin_amdgcn_mfma_f32_16x16x32_bf16(
                    af[mi], bfr[ni], acc[mi][ni], 0, 0, 0);

        if (t + 3 < NTk) G256_STAGE(t + 3);
    }

#pragma unroll
    for (int ni = 0; ni < 4; ni++) {
        const int col = col0 + wc * 64 + ni * 16 + l16;
        float badd = 0.f;
        if constexpr (HAS_BIAS) badd = bias[col];
        float qs = 1.f;
        if constexpr (QSCALE)
            qs = (((col0 + wc * 64 + ni * 16) % 192) < 64) ? KLOG2E : 1.f;
#pragma unroll
        for (int mi = 0; mi < 8; mi++) {
#pragma unroll
            for (int r = 0; r < 4; r++) {
                const int row = row0 + wr * 128 + mi * 16 + quad * 4 + r;
                float v = acc[mi][ni][r] + badd;
                if constexpr (QSCALE) v *= qs;
                if constexpr (RELU) v = fmaxf(v, 0.f);
                out[(size_t)row * N + col] = (unsigned short)f2bf(v);
            }
        }
    }
}

// ---------------------------------------------------------------------------
// NON-SPLIT 128x128 ring GEMM (4 waves, BK=32, 4-slot x 16 KB = 64 KB LDS,
// counted vmcnt) with bias/QSCALE/RELU bf16 epilogue. Used for qkv only:
// grid 32x24 = 768 blocks = 100% CU coverage at 2/CU (the 256^2 ring gave
// only 192 blocks = 75% of CUs for qkv's shape). r13 verified: session best.
// ---------------------------------------------------------------------------
#define G128R_STAGE(tile_)                                                    \
    do {                                                                      \
        char* sb_ = smem + (size_t)((tile_) & 3) * 16384;                     \
        const int kb_ = (tile_) << 5;                                         \
        __builtin_amdgcn_global_load_lds(                                     \
            (const GLOBAL_AS void*)(agp0 + kb_),                              \
            (LDS_AS void*)(sb_ + adst0), 16, 0, 0);                           \
        __builtin_amdgcn_global_load_lds(                                     \
            (const GLOBAL_AS void*)(agp1 + kb_),                              \
            (LDS_AS void*)(sb_ + adst1), 16, 0, 0);                           \
        __builtin_amdgcn_global_load_lds(                                     \
            (const GLOBAL_AS void*)(bgp0 + kb_),                              \
            (LDS_AS void*)(sb_ + 8192 + adst0), 16, 0, 0);                    \
        __builtin_amdgcn_global_load_lds(                                     \
            (const GLOBAL_AS void*)(bgp1 + kb_),                              \
            (LDS_AS void*)(sb_ + 8192 + adst1), 16, 0, 0);                    \
    } while (0)

template<bool HAS_BIAS, bool RELU, bool QSCALE>
__global__ __launch_bounds__(256) void gemm128r_kernel(
    const unsigned short* __restrict__ A,
    const unsigned short* __restrict__ Bt,
    const float* __restrict__ bias,
    unsigned short* __restrict__ out,
    int M, int N, int K)
{
    extern __shared__ char smem[];

    const int tid  = threadIdx.x;
    const int wave = tid >> 6;
    const int lane = tid & 63;
    const int quad = lane >> 4;
    const int l16  = lane & 15;

    const int row0 = blockIdx.x * 128;
    const int col0 = blockIdx.y * 128;

    const int ldrow = lane >> 2;                                 // 0..15
    const int ldk   = (((lane & 3) ^ ((ldrow >> 1) & 3)) * 8);   // swizzled
    const unsigned short* agp0 = A  + (size_t)(row0 + wave * 32 + ldrow) * K + ldk;
    const unsigned short* agp1 = agp0 + (size_t)16 * K;
    const unsigned short* bgp0 = Bt + (size_t)(col0 + wave * 32 + ldrow) * K + ldk;
    const unsigned short* bgp1 = bgp0 + (size_t)16 * K;

    const int adst0 = (wave * 32 + ldrow) * 64 + (lane & 3) * 16;
    const int adst1 = adst0 + 16 * 64;

    const int wm = (wave >> 1) * 64;
    const int wn = (wave & 1) * 64;
    const int rsw = (quad ^ ((l16 >> 1) & 3)) * 8;

    const int NTk = K >> 5;          // K-tiles of 32

    f32x4 acc[4][4] = {};

    // prologue: stage tiles 0,1,2
    G128R_STAGE(0);
    if (1 < NTk) G128R_STAGE(1);
    if (2 < NTk) G128R_STAGE(2);

    for (int t = 0; t < NTk; t++) {
        if (t + 2 < NTk)
            asm volatile("s_waitcnt vmcnt(8)\n\ts_barrier" ::: "memory");
        else if (t + 1 < NTk)
            asm volatile("s_waitcnt vmcnt(4)\n\ts_barrier" ::: "memory");
        else
            asm volatile("s_waitcnt vmcnt(0)\n\ts_barrier" ::: "memory");

        const short* sA = (const short*)(smem + (size_t)(t & 3) * 16384);
        const short* sB = sA + 4096;

        bf16x8 af[4], bfr[4];
#pragma unroll
        for (int mi = 0; mi < 4; mi++)
            af[mi] = *reinterpret_cast<const bf16x8*>(
                &sA[(wm + mi * 16 + l16) * 32 + rsw]);
#pragma unroll
        for (int ni = 0; ni < 4; ni++)
            bfr[ni] = *reinterpret_cast<const bf16x8*>(
                &sB[(wn + ni * 16 + l16) * 32 + rsw]);
#pragma unroll
        for (int mi = 0; mi < 4; mi++)
#pragma unroll
            for (int ni = 0; ni < 4; ni++)
                acc[mi][ni] = __builtin_amdgcn_mfma_f32_16x16x32_bf16(
                    af[mi], bfr[ni], acc[mi][ni], 0, 0, 0);

        if (t + 3 < NTk) G128R_STAGE(t + 3);
    }

#pragma unroll
    for (int ni = 0; ni < 4; ni++) {
        const int col = col0 + wn + ni * 16 + l16;
        float badd = 0.f;
        if constexpr (HAS_BIAS) badd = bias[col];
        float qs = 1.f;
        if constexpr (QSCALE)
            qs = (((col0 + wn + ni * 16) % 192) < 64) ? KLOG2E : 1.f;
#pragma unroll
        for (int mi = 0; mi < 4; mi++) {
#pragma unroll
            for (int r = 0; r < 4; r++) {
                const int row = row0 + wm + mi * 16 + quad * 4 + r;
                float v = acc[mi][ni][r] + badd;
                if constexpr (QSCALE) v *= qs;
                if constexpr (RELU) v = fmaxf(v, 0.f);
                out[(size_t)row * N + col] = (unsigned short)f2bf(v);
            }
        }
    }
}

// ---------------------------------------------------------------------------
// Split-K 128x128 GEMM, BK=32, 4-slot LDS ring with COUNTED vmcnt pipeline —
// r10 verified. Raw f32 partials. Used for wo and ffn2.
// ---------------------------------------------------------------------------
#define GSK_STAGE(tile_)                                                      \
    do {                                                                      \
        char* sb_ = smem + (size_t)((tile_) & 3) * 16384;                     \
        const int kb_ = (tile_) << 5;                                         \
        __builtin_amdgcn_global_load_lds(                                     \
            (const GLOBAL_AS void*)(agp0 + kb_),                              \
            (LDS_AS void*)(sb_ + adst0), 16, 0, 0);                           \
        __builtin_amdgcn_global_load_lds(                                     \
            (const GLOBAL_AS void*)(agp1 + kb_),                              \
            (LDS_AS void*)(sb_ + adst1), 16, 0, 0);                           \
        __builtin_amdgcn_global_load_lds(                                     \
            (const GLOBAL_AS void*)(bgp0 + kb_),                              \
            (LDS_AS void*)(sb_ + 8192 + adst0), 16, 0, 0);                    \
        __builtin_amdgcn_global_load_lds(                                     \
            (const GLOBAL_AS void*)(bgp1 + kb_),                              \
            (LDS_AS void*)(sb_ + 8192 + adst1), 16, 0, 0);                    \
    } while (0)

__global__ __launch_bounds__(256) void gemm128_sk_kernel(
    const unsigned short* __restrict__ A,
    const unsigned short* __restrict__ Bt,
    float* __restrict__ out0,
    float* __restrict__ out1,
    int M, int N, int K)
{
    extern __shared__ char smem[];

    const int tid  = threadIdx.x;
    const int wave = tid >> 6;
    const int lane = tid & 63;
    const int quad = lane >> 4;
    const int l16  = lane & 15;

    const int row0 = blockIdx.x * 128;
    const int col0 = blockIdx.y * 128;
    const int z    = blockIdx.z;
    const int Kh   = K >> 1;

    const unsigned short* Az  = A  + (size_t)z * Kh;
    const unsigned short* Btz = Bt + (size_t)z * Kh;
    float* out = z ? out1 : out0;

    const int ldrow = lane >> 2;                                 // 0..15
    const int ldk   = (((lane & 3) ^ ((ldrow >> 1) & 3)) * 8);   // swizzled
    const unsigned short* agp0 = Az  + (size_t)(row0 + wave * 32 + ldrow) * K + ldk;
    const unsigned short* agp1 = agp0 + (size_t)16 * K;
    const unsigned short* bgp0 = Btz + (size_t)(col0 + wave * 32 + ldrow) * K + ldk;
    const unsigned short* bgp1 = bgp0 + (size_t)16 * K;

    // LDS byte destinations within a slot (A at 0, B at +8192):
    // row = wave*32+ldrow (+16), 64 B/row, slot (lane&3)*16.
    const int adst0 = (wave * 32 + ldrow) * 64 + (lane & 3) * 16;
    const int adst1 = adst0 + 16 * 64;

    const int wm = (wave >> 1) * 64;
    const int wn = (wave & 1) * 64;
    const int rsw = (quad ^ ((l16 >> 1) & 3)) * 8;

    const int NTk = Kh >> 5;         // K-tiles of 32

    f32x4 acc[4][4] = {};

    // prologue: stage tiles 0,1,2
    GSK_STAGE(0);
    if (1 < NTk) GSK_STAGE(1);
    if (2 < NTk) GSK_STAGE(2);

    for (int t = 0; t < NTk; t++) {
        if (t + 2 < NTk)
            asm volatile("s_waitcnt vmcnt(8)\n\ts_barrier" ::: "memory");
        else if (t + 1 < NTk)
            asm volatile("s_waitcnt vmcnt(4)\n\ts_barrier" ::: "memory");
        else
            asm volatile("s_waitcnt vmcnt(0)\n\ts_barrier" ::: "memory");

        const short* sA = (const short*)(smem + (size_t)(t & 3) * 16384);
        const short* sB = sA + 4096;

        bf16x8 af[4], bfr[4];
#pragma unroll
        for (int mi = 0; mi < 4; mi++)
            af[mi] = *reinterpret_cast<const bf16x8*>(
                &sA[(wm + mi * 16 + l16) * 32 + rsw]);
#pragma unroll
        for (int ni = 0; ni < 4; ni++)
            bfr[ni] = *reinterpret_cast<const bf16x8*>(
                &sB[(wn + ni * 16 + l16) * 32 + rsw]);
#pragma unroll
        for (int mi = 0; mi < 4; mi++)
#pragma unroll
            for (int ni = 0; ni < 4; ni++)
                acc[mi][ni] = __builtin_amdgcn_mfma_f32_16x16x32_bf16(
                    af[mi], bfr[ni], acc[mi][ni], 0, 0, 0);

        if (t + 3 < NTk) GSK_STAGE(t + 3);
    }

#pragma unroll
    for (int ni = 0; ni < 4; ni++) {
        const int col = col0 + wn + ni * 16 + l16;
#pragma unroll
        for (int mi = 0; mi < 4; mi++)
#pragma unroll
            for (int r = 0; r < 4; r++) {
                const int row = row0 + wm + mi * 16 + quad * 4 + r;
                out[(size_t)row * N + col] = acc[mi][ni][r];
            }
    }
}

// ---------------------------------------------------------------------------
// Flash attention v9 (r10-exact — best measured config, 66.4 us):
// 128-row Q tile, 8 waves (512 thr), key-split. Waves 0-3 process keys
// [0,1024), waves 4-7 keys [1024,2048); each group has its own K/V LDS stage
// (2-MFMA-per-LDS-read reuse) at 2 blocks/CU = 16 waves/CU. Un-normalized
// softmax (p=2^s) => partials combine by plain addition in an LDS epilogue.
// The P LDS round-trip is LOAD-BEARING: it decouples softmax and PV phases
// so sibling waves overlap (r11's in-register P serialized the chain and
// REGRESSED 66->76us). setprio/perm-pack also regressed (r4). FROZEN.
// ---------------------------------------------------------------------------
__global__ __launch_bounds__(512) void attn_kernel(
    const unsigned short* __restrict__ qkv,
    unsigned short* __restrict__ ao)
{
    extern __shared__ char smem[];

    const int qt = blockIdx.x;          // 128-row query tile
    const int h  = blockIdx.y;
    const int b  = blockIdx.z;

    const int tid  = threadIdx.x;
    const int wave = tid >> 6;
    const int g    = wave >> 2;         // key-split group (0: keys lo, 1: hi)
    const int gw   = wave & 3;          // wave within group -> 32-row slice
    const int lane = tid & 63;
    const int quad = lane >> 4;
    const int l16  = lane & 15;
    const int gtid = tid & 255;         // thread within group (staging)

    short* Ks = (short*)smem + g * (64 * 72);            // [key][dim] swizzled
    short* Vt = (short*)(smem + 18432) + g * (64 * 72);  // [dim][pos] swizzled
    short* Ps = (short*)(smem + 36864) + wave * (32 * 72); // per-wave P

    bf16x8 qf[2][2];
#pragma unroll
    for (int mi = 0; mi < 2; mi++) {
        const int qrow = qt * 128 + gw * 32 + mi * 16 + l16;
        const unsigned short* qb = qkv + (size_t)(b * S_ + qrow) * 3072 + h * 192;
        qf[mi][0] = *reinterpret_cast<const bf16x8*>(qb + quad * 8);
        qf[mi][1] = *reinterpret_cast<const bf16x8*>(qb + 32 + quad * 8);
    }

    // all-ones B fragment for the l row-sum MFMA
    bf16x8 vones;
#pragma unroll
    for (int j = 0; j < 8; j++) vones[j] = (short)0x3F80;

    f32x4 o[2][4] = {};
    f32x4 o_l[2] = {};                // l accumulator (row sums of P)

    const int skey = gtid >> 3;       // 0..31 (K rows)
    const int soct = gtid & 7;        // 0..7  (dim octet)
    const int vp   = gtid >> 3;       // 0..31 (V key pair id)
    const int kA   = (vp & 15) + ((vp >> 4) << 5);
    const int kB   = kA + 16;
    const int posA = 4 * (vp & 15) + 2 * (vp >> 4);
    const int vwr  = ((posA >> 3) ^ soct) * 8 + (posA & 7);

    const int kb0   = g * (S_ / 2);
    const int kbend = kb0 + S_ / 2;

    const unsigned short* kbase0 = qkv + (size_t)(b * S_) * 3072 + h * 192 + 64;
    const unsigned short* vbase0 = qkv + (size_t)(b * S_) * 3072 + h * 192 + 128;

    bf16x8 pk0 = *reinterpret_cast<const bf16x8*>(kbase0 + (size_t)(kb0 + skey) * 3072 + soct * 8);
    bf16x8 pk1 = *reinterpret_cast<const bf16x8*>(kbase0 + (size_t)(kb0 + skey + 32) * 3072 + soct * 8);
    bf16x8 pv0 = *reinterpret_cast<const bf16x8*>(vbase0 + (size_t)(kb0 + kA) * 3072 + soct * 8);
    bf16x8 pv1 = *reinterpret_cast<const bf16x8*>(vbase0 + (size_t)(kb0 + kB) * 3072 + soct * 8);

    for (int kb = kb0; kb < kbend; kb += 64) {
        {
            const int woct0 = soct ^ ((skey >> 3) & 1);
            *reinterpret_cast<bf16x8*>(&Ks[skey * 72 + woct0 * 8]) = pk0;
            const int woct1 = soct ^ (((skey + 32) >> 3) & 1);
            *reinterpret_cast<bf16x8*>(&Ks[(skey + 32) * 72 + woct1 * 8]) = pk1;
#pragma unroll
            for (int j = 0; j < 8; j++) {
                const int d = soct * 8 + j;
                const unsigned int val =
                    (unsigned int)(unsigned short)pv0[j] |
                    ((unsigned int)(unsigned short)pv1[j] << 16);
                *reinterpret_cast<unsigned int*>(&Vt[d * 72 + vwr]) = val;
            }
        }
        __syncthreads();

        {
            const int kbn = (kb + 64 < kbend) ? kb + 64 : kb;
            pk0 = *reinterpret_cast<const bf16x8*>(
                kbase0 + (size_t)(kbn + skey) * 3072 + soct * 8);
            pk1 = *reinterpret_cast<const bf16x8*>(
                kbase0 + (size_t)(kbn + skey + 32) * 3072 + soct * 8);
            pv0 = *reinterpret_cast<const bf16x8*>(
                vbase0 + (size_t)(kbn + kA) * 3072 + soct * 8);
            pv1 = *reinterpret_cast<const bf16x8*>(
                vbase0 + (size_t)(kbn + kB) * 3072 + soct * 8);
        }

        // --- QK^T ---
        f32x4 s[2][4] = {};
#pragma unroll
        for (int c2 = 0; c2 < 2; c2++) {
#pragma unroll
            for (int nt = 0; nt < 4; nt++) {
                const int key = nt * 16 + l16;
                const int roct = (c2 * 4 + quad) ^ ((key >> 3) & 1);
                bf16x8 kf = *reinterpret_cast<const bf16x8*>(
                    &Ks[key * 72 + roct * 8]);
                s[0][nt] = __builtin_amdgcn_mfma_f32_16x16x32_bf16(qf[0][c2], kf, s[0][nt], 0, 0, 0);
                s[1][nt] = __builtin_amdgcn_mfma_f32_16x16x32_bf16(qf[1][c2], kf, s[1][nt], 0, 0, 0);
            }
        }

        // --- softmax: p = 2^s; packed cvt; b64 store at pos 4*l16 ---
#pragma unroll
        for (int mi = 0; mi < 2; mi++) {
#pragma unroll
            for (int r = 0; r < 4; r++) {
                const int m = mi * 16 + quad * 4 + r;
                const float p0 = exp2f(s[mi][0][r]);
                const float p1 = exp2f(s[mi][1][r]);
                const float p2 = exp2f(s[mi][2][r]);
                const float p3 = exp2f(s[mi][3][r]);
                uint2 w;
                w.x = pk2bf(p0, p1);
                w.y = pk2bf(p2, p3);
                *reinterpret_cast<uint2*>(&Ps[m * 72 + l16 * 4]) = w;
            }
        }

        // --- PV + l row-sum via ones MFMA ---
#pragma unroll
        for (int c2 = 0; c2 < 2; c2++) {
            bf16x8 pf[2];
#pragma unroll
            for (int mi = 0; mi < 2; mi++) {
                const int m = mi * 16 + l16;
                pf[mi] = *reinterpret_cast<const bf16x8*>(
                    &Ps[m * 72 + c2 * 32 + quad * 8]);
            }
#pragma unroll
            for (int ct = 0; ct < 4; ct++) {
                const int row = ct * 16 + l16;
                const int blk = (c2 * 4 + quad) ^ (row >> 3);
                bf16x8 vf = *reinterpret_cast<const bf16x8*>(
                    &Vt[row * 72 + blk * 8]);
                o[0][ct] = __builtin_amdgcn_mfma_f32_16x16x32_bf16(pf[0], vf, o[0][ct], 0, 0, 0);
                o[1][ct] = __builtin_amdgcn_mfma_f32_16x16x32_bf16(pf[1], vf, o[1][ct], 0, 0, 0);
            }
            o_l[0] = __builtin_amdgcn_mfma_f32_16x16x32_bf16(pf[0], vones, o_l[0], 0, 0, 0);
            o_l[1] = __builtin_amdgcn_mfma_f32_16x16x32_bf16(pf[1], vones, o_l[1], 0, 0, 0);
        }
        __syncthreads();
    }

    // --- key-split combine: group 1 parks partials in LDS (f32, exact), ---
    // --- group 0 adds, normalizes, stores.                              ---
    float* ex = (float*)smem;
    const int slot = (gw * 64 + lane) * 40;   // 32 o floats + 8 l floats
    if (g == 1) {
#pragma unroll
        for (int mi = 0; mi < 2; mi++) {
#pragma unroll
            for (int ct = 0; ct < 4; ct++)
                *reinterpret_cast<f32x4*>(&ex[slot + mi * 16 + ct * 4]) = o[mi][ct];
            *reinterpret_cast<f32x4*>(&ex[slot + 32 + mi * 4]) = o_l[mi];
        }
    }
    __syncthreads();
    if (g == 0) {
#pragma unroll
        for (int mi = 0; mi < 2; mi++) {
#pragma unroll
            for (int ct = 0; ct < 4; ct++) {
                f32x4 t = *reinterpret_cast<const f32x4*>(&ex[slot + mi * 16 + ct * 4]);
                o[mi][ct] += t;
            }
            f32x4 tl = *reinterpret_cast<const f32x4*>(&ex[slot + 32 + mi * 4]);
            o_l[mi] += tl;
        }
#pragma unroll
        for (int mi = 0; mi < 2; mi++) {
            f32x4 rl;
#pragma unroll
            for (int r = 0; r < 4; r++) rl[r] = 1.f / o_l[mi][r];
#pragma unroll
            for (int ct = 0; ct < 4; ct++)
#pragma unroll
                for (int r = 0; r < 4; r++) {
                    const int row = qt * 128 + gw * 32 + mi * 16 + quad * 4 + r;
                    ao[(size_t)(b * S_ + row) * D_ + h * HD_ + ct * 16 + l16] =
                        (unsigned short)f2bf(o[mi][ct][r] * rl[r]);
                }
        }
    }
}

// ---------------------------------------------------------------------------
// LN over D=1024 with fused partial-sum + bias + residual; packed stores.
// ---------------------------------------------------------------------------
template<int RESM, bool FLAG_OUT>
__global__ __launch_bounds__(256) void ln_sum_kernel(
    const float* __restrict__ p0,
    const float* __restrict__ p1,
    const float* __restrict__ bias,
    const unsigned short* __restrict__ resb,
    const float* __restrict__ resf,
    const float* __restrict__ g,
    const float* __restrict__ bt,
    const int* __restrict__ flags,
    void* __restrict__ out)
{
    const int row = blockIdx.x;
    const int tid = threadIdx.x;
    const int c0  = tid * 4;
    const size_t base = (size_t)row * D_ + c0;

    float4 a = *reinterpret_cast<const float4*>(p0 + base);
    float4 bq = *reinterpret_cast<const float4*>(p1 + base);
    float4 bi = *reinterpret_cast<const float4*>(bias + c0);

    float v[4] = {a.x + bq.x + bi.x, a.y + bq.y + bi.y,
                  a.z + bq.z + bi.z, a.w + bq.w + bi.w};

    if constexpr (RESM == 1) {
        if (flags[0]) {
            float4 rv = *reinterpret_cast<const float4*>(resf + base);
            v[0] += rv.x; v[1] += rv.y; v[2] += rv.z; v[3] += rv.w;
        } else {
            uint2 rv = *reinterpret_cast<const uint2*>(resb + base);
            v[0] += bf2f((unsigned short)(rv.x & 0xFFFF));
            v[1] += bf2f((unsigned short)(rv.x >> 16));
            v[2] += bf2f((unsigned short)(rv.y & 0xFFFF));
            v[3] += bf2f((unsigned short)(rv.y >> 16));
        }
    } else {
        uint2 rv = *reinterpret_cast<const uint2*>(resb + base);
        v[0] += bf2f((unsigned short)(rv.x & 0xFFFF));
        v[1] += bf2f((unsigned short)(rv.x >> 16));
        v[2] += bf2f((unsigned short)(rv.y & 0xFFFF));
        v[3] += bf2f((unsigned short)(rv.y >> 16));
    }

    float s = v[0] + v[1] + v[2] + v[3];
    float sq = v[0] * v[0] + v[1] * v[1] + v[2] * v[2] + v[3] * v[3];
#pragma unroll
    for (int msk = 1; msk < 64; msk <<= 1) {
        s += __shfl_xor(s, msk);
        sq += __shfl_xor(sq, msk);
    }
    __shared__ float ss[4], ssq[4];
    if ((tid & 63) == 0) { ss[tid >> 6] = s; ssq[tid >> 6] = sq; }
    __syncthreads();
    s = ss[0] + ss[1] + ss[2] + ss[3];
    sq = ssq[0] + ssq[1] + ssq[2] + ssq[3];

    const float mean = s * (1.f / D_);
    const float var = sq * (1.f / D_) - mean * mean;
    const float rinv = rsqrtf(var + EPS_);

    float w[4];
#pragma unroll
    for (int i = 0; i < 4; i++)
        w[i] = (v[i] - mean) * rinv * g[c0 + i] + bt[c0 + i];

    int outF32 = 0;
    if constexpr (FLAG_OUT) outF32 = flags[0];

    if (FLAG_OUT && outF32) {
        float4 o4 = {w[0], w[1], w[2], w[3]};
        *reinterpret_cast<float4*>((float*)out + base) = o4;
    } else {
        uint2 o2;
        o2.x = pk2bf(w[0], w[1]);
        o2.y = pk2bf(w[2], w[3]);
        *reinterpret_cast<uint2*>((unsigned short*)out + base) = o2;
    }
}

// ---------------------------------------------------------------------------
extern "C" void kernel_launch(void* const* d_in, const int* in_sizes, int n_in,
                              void* d_out, int out_size, void* d_ws, size_t ws_size,
                              hipStream_t stream) {
    char* ws = (char*)d_ws;

    int*            flags = (int*)(ws + 0);
    unsigned short* xb    = (unsigned short*)(ws + 256);
    unsigned short* wqkvT = (unsigned short*)(ws + 8388864);
    unsigned short* woT   = (unsigned short*)(ws + 14680320);
    unsigned short* w1T   = (unsigned short*)(ws + 16777472);
    unsigned short* w2T   = (unsigned short*)(ws + 25166080);
    float*          bof   = (float*)(ws + 33554688);
    float*          g1f   = (float*)(ws + 33558784);
    float*          bt1f  = (float*)(ws + 33562880);
    float*          b1f   = (float*)(ws + 33566976);
    float*          b2f   = (float*)(ws + 33583360);
    float*          g2f   = (float*)(ws + 33587456);
    float*          bt2f  = (float*)(ws + 33591552);
    unsigned short* qkv   = (unsigned short*)(ws + 33595648);
    unsigned short* ao    = (unsigned short*)(ws + 256);          // reuse xb
    unsigned short* y     = (unsigned short*)(ws + 33595648);     // reuse qkv
    unsigned short* hbuf  = (unsigned short*)(ws + 41984256);
    float*          part0 = (float*)(ws + 58761472);
    float*          part1 = (float*)(ws + 75538688);
    float*          hpart0= (float*)(ws + 256);                   // reuse ao slot

    dim3 blk(256);

    // allow >64KB dynamic LDS: attn 73728, 256^2 ring 131072; 128^2 rings 65536.
    static int attr_done = 0;
    if (!attr_done) {
        hipFuncSetAttribute(reinterpret_cast<const void*>(attn_kernel),
                            hipFuncAttributeMaxDynamicSharedMemorySize, 73728);
        hipFuncSetAttribute(
            reinterpret_cast<const void*>(&gemm256_kernel<true, true, false>),
            hipFuncAttributeMaxDynamicSharedMemorySize, 131072);
        hipFuncSetAttribute(
            reinterpret_cast<const void*>(&gemm128r_kernel<false, false, true>),
            hipFuncAttributeMaxDynamicSharedMemorySize, 65536);
        hipFuncSetAttribute(reinterpret_cast<const void*>(gemm128_sk_kernel),
                            hipFuncAttributeMaxDynamicSharedMemorySize, 65536);
        attr_done = 1;
    }

    DetectArgs da;
    for (int i = 0; i < 12; i++) {
        da.p[i] = (const unsigned short*)d_in[i];
        da.n[i] = in_sizes[i];
    }
    detect_kernel<<<dim3(12), blk, 0, stream>>>(da, flags);

    // x convert + small-vector converts (fused)
    VecArgs va;
    const int vidx[7] = {3, 4, 5, 7, 9, 10, 11};
    float* vdst[7] = {bof, g1f, bt1f, b1f, b2f, g2f, bt2f};
    for (int i = 0; i < 7; i++) {
        va.src[i] = d_in[vidx[i]];
        va.dst[i] = vdst[i];
        va.n[i]   = in_sizes[vidx[i]];
        va.fidx[i] = vidx[i];
    }
    conv_x_vecs_kernel<<<dim3((NT * D_ + 255) / 256), blk, 0, stream>>>(
        d_in[0], xb, NT * D_, va, flags);

    // 4 weight transposes (fused via z-sections)
    TArgs ta;
    ta.src[0] = d_in[1]; ta.dst[0] = wqkvT; ta.K[0] = D_;  ta.N[0] = 3 * D_; ta.fidx[0] = 1;
    ta.src[1] = d_in[2]; ta.dst[1] = woT;   ta.K[1] = D_;  ta.N[1] = D_;     ta.fidx[1] = 2;
    ta.src[2] = d_in[6]; ta.dst[2] = w1T;   ta.K[2] = D_;  ta.N[2] = FF_;    ta.fidx[2] = 6;
    ta.src[3] = d_in[8]; ta.dst[3] = w2T;   ta.K[3] = FF_; ta.N[3] = D_;     ta.fidx[3] = 8;
    ta.start[0] = 0;
    for (int wI = 0; wI < 4; wI++)
        ta.start[wI + 1] = ta.start[wI] + (ta.K[wI] / 32) * (ta.N[wI] / 32);
    conv_t_all_kernel<<<dim3(ta.start[4]), blk, 0, stream>>>(ta, flags);

    // 1) qkv = x @ w_qkv, Q part pre-scaled by KLOG2E (128^2 ring, r13-proven:
    //    grid 768 = full CU coverage at 2/CU)
    gemm128r_kernel<false, false, true>
        <<<dim3(NT / 128, 3072 / 128), blk, 65536, stream>>>(
            xb, wqkvT, nullptr, qkv, NT, 3072, 1024);

    // 2) attention -> ao bf16 (128-row tiles, 8-wave key-split blocks)
    attn_kernel<<<dim3(S_ / 128, H_, B_), dim3(512), 73728, stream>>>(qkv, ao);

    // 3) wo projection, split-K x2 ring pipeline -> raw f32 partials
    gemm128_sk_kernel<<<dim3(NT / 128, 1024 / 128, 2), blk, 65536, stream>>>(
        ao, woT, part0, part1, NT, 1024, 1024);

    // 4) y = LN(part0+part1 + b_o + x)
    ln_sum_kernel<1, false><<<dim3(NT), blk, 0, stream>>>(
        part0, part1, bof, (const unsigned short*)d_in[0], (const float*)d_in[0],
        g1f, bt1f, flags, y);

    // 5) h = relu(y @ w1 + b1) (256^2 ring, r13-proven: grid 256 = 1/CU exact;
    //    r14 showed 128^2 was worse here — no coverage deficit to fix)
    gemm256_kernel<true, true, false>
        <<<dim3(NT / 256, 4096 / 256), dim3(512), 131072, stream>>>(
            y, w1T, b1f, hbuf, NT, 4096, 1024);

    // 6) FFN2, split-K x2 ring pipeline -> raw f32 partials
    gemm128_sk_kernel<<<dim3(NT / 128, 1024 / 128, 2), blk, 65536, stream>>>(
        hbuf, w2T, hpart0, part1, NT, 1024, 4096);

    // 7) out = LN(hpart0+part1 + b2 + y), output dtype per flags[0]
    ln_sum_kernel<2, true><<<dim3(NT), blk, 0, stream>>>(
        hpart0, part1, b2f, y, nullptr, g2f, bt2f, flags, d_out);
}